// Round 6
// baseline (1786.718 us; speedup 1.0000x reference)
//
#include <hip/hip_runtime.h>
#include <cstdint>
#include <cstddef>
#include <cmath>

// DiffusionActiveInference on MI355X (gfx950).
// R6: (1) REVERT to row-major block order everywhere: grid.x = row blocks
// (multiple of 8) -> XCD = rowBlk%8 affinity (all col-blocks of a row band
// share one XCD L2). R5's col-major put A-band sharers on 8 non-coherent
// XCDs -> 133 MB fetch vs 41 MB. (2) pL2 and vdot merged into one dispatch
// (independent after pd1v). (3) all weight prep in one mega kernel.

typedef __bf16 bf16;
typedef __attribute__((ext_vector_type(8))) __bf16 bf16x8;
typedef __attribute__((ext_vector_type(4))) __bf16 bf16x4;
typedef __attribute__((ext_vector_type(4))) float f32x4;

static constexpr int BATCH = 1024, NTRAJ = 16, HORIZON = 5;
static constexpr int MR = NTRAJ * BATCH;  // 16384 GEMM rows
static constexpr float ENT_C = 1.4189385332046727f;  // 0.5*(1+log(2*pi))
static constexpr float SUMDISC = 4.90099501f;        // sum 0.99^t, t=0..4

// ---- async global->LDS, 16B per lane ----------------------------------
__device__ __forceinline__ void gld_lds16(const bf16* g, const bf16* l) {
  typedef __attribute__((address_space(1))) const uint32_t gq_t;
  typedef __attribute__((address_space(3))) uint32_t lq_t;
  gq_t* gp = (gq_t*)(uintptr_t)g;
  lq_t* lp = (lq_t*)(uint32_t)(uintptr_t)l;
  __builtin_amdgcn_global_load_lds(gp, lp, 16, 0, 0);
}

__device__ __forceinline__ float silu(float x) {
  return x / (1.f + __expf(-x));
}

#define MFMA16(a, b, c) __builtin_amdgcn_mfma_f32_16x16x32_bf16((a), (b), (c), 0, 0, 0)

// ---- generic GEMM: C = maybe_silu(A[M,K](lda) @ Bt[N,K]^T + bias) -----
// grid (M/128, N/128) ROW-major (x=row -> XCD affinity). BK=64 dual panels.
// silu iff colBlk < act_cols; out to C1 else C2 at (col - act_cols).
__global__ __launch_bounds__(256) void gemm128(
    const bf16* __restrict__ A, int lda, int K, const bf16* __restrict__ Bt,
    const float* __restrict__ bias, int act_cols,
    bf16* __restrict__ C1, bf16* __restrict__ C2, int ldc) {
  __shared__ alignas(16) bf16 As0[128 * 32], As1[128 * 32];
  __shared__ alignas(16) bf16 Bs0[128 * 32], Bs1[128 * 32];
  const int tid = threadIdx.x, wave = tid >> 6, lane = tid & 63;
  const int quad = lane >> 4, l16 = lane & 15;
  const int rowBlk = blockIdx.x * 128, colBlk = blockIdx.y * 128;
  const int wr = wave >> 1, wc = wave & 1;
  const int srow = lane >> 2, skel = (lane & 3) * 8;

  const bf16* gA0 = A + (size_t)(rowBlk + wave * 32 + srow) * lda + skel;
  const bf16* gA1 = gA0 + (size_t)16 * lda;
  const bf16* gB0 = Bt + (size_t)(colBlk + wave * 32 + srow) * K + skel;
  const bf16* gB1 = gB0 + (size_t)16 * K;
  bf16* const lA0 = As0 + wave * 32 * 32;
  bf16* const lA0b = As0 + (wave * 32 + 16) * 32;
  bf16* const lA1 = As1 + wave * 32 * 32;
  bf16* const lA1b = As1 + (wave * 32 + 16) * 32;
  bf16* const lB0 = Bs0 + wave * 32 * 32;
  bf16* const lB0b = Bs0 + (wave * 32 + 16) * 32;
  bf16* const lB1 = Bs1 + wave * 32 * 32;
  bf16* const lB1b = Bs1 + (wave * 32 + 16) * 32;

  f32x4 acc[4][4] = {};
  for (int k0 = 0; k0 < K; k0 += 64) {
    gld_lds16(gA0 + k0, lA0);
    gld_lds16(gA1 + k0, lA0b);
    gld_lds16(gA0 + k0 + 32, lA1);
    gld_lds16(gA1 + k0 + 32, lA1b);
    gld_lds16(gB0 + k0, lB0);
    gld_lds16(gB1 + k0, lB0b);
    gld_lds16(gB0 + k0 + 32, lB1);
    gld_lds16(gB1 + k0 + 32, lB1b);
    __syncthreads();
#pragma unroll
    for (int ks = 0; ks < 2; ++ks) {
      const bf16* aRd = (ks ? As1 : As0) + (wr * 64 + l16) * 32 + quad * 8;
      const bf16* bRd = (ks ? Bs1 : Bs0) + (wc * 64 + l16) * 32 + quad * 8;
      bf16x8 af[4], bfr[4];
#pragma unroll
      for (int i = 0; i < 4; ++i) {
        af[i] = *(const bf16x8*)(aRd + i * 16 * 32);
        bfr[i] = *(const bf16x8*)(bRd + i * 16 * 32);
      }
#pragma unroll
      for (int mi = 0; mi < 4; ++mi)
#pragma unroll
        for (int ni = 0; ni < 4; ++ni)
          acc[mi][ni] = MFMA16(bfr[ni], af[mi], acc[mi][ni]);
    }
    __syncthreads();
  }

  const bool doAct = (colBlk < act_cols);
  bf16* const Cp = doAct ? C1 : C2;
  const int cShift = doAct ? 0 : act_cols;
#pragma unroll
  for (int mi = 0; mi < 4; ++mi) {
    const int row = rowBlk + wr * 64 + mi * 16 + l16;
#pragma unroll
    for (int ni = 0; ni < 4; ++ni) {
      const int col0 = colBlk + wc * 64 + ni * 16 + quad * 4;
      const f32x4 bb = *(const f32x4*)(bias + col0);
      bf16x4 o;
#pragma unroll
      for (int r = 0; r < 4; ++r) {
        float x = acc[mi][ni][r] + bb[r];
        if (doAct) x = silu(x);
        o[r] = (bf16)x;
      }
      *(bf16x4*)(Cp + (size_t)row * ldc + (col0 - cShift)) = o;
    }
  }
}

// ---- per-step trunk: [policy-L1 | dyn-L1z | value-L1] in one GEMM -----
// grid (M/128, 24) row-major. K=256. Cols 0..1023 silu->Ha; 1024..2047
// linear->Hp; 2048..3071 silu(+vbias[t-1])->Hv.
__global__ __launch_bounds__(256) void gemm_pd1v(
    const bf16* __restrict__ A, const bf16* __restrict__ Bt,
    const float* __restrict__ pdb1, const float* __restrict__ vbiasT,
    bf16* __restrict__ Ha, bf16* __restrict__ Hp, bf16* __restrict__ Hv) {
  __shared__ alignas(16) bf16 As0[128 * 32], As1[128 * 32];
  __shared__ alignas(16) bf16 Bs0[128 * 32], Bs1[128 * 32];
  const int tid = threadIdx.x, wave = tid >> 6, lane = tid & 63;
  const int quad = lane >> 4, l16 = lane & 15;
  const int rowBlk = blockIdx.x * 128, colBlk = blockIdx.y * 128;
  const int wr = wave >> 1, wc = wave & 1;
  const int srow = lane >> 2, skel = (lane & 3) * 8;

  const bf16* gA0 = A + (size_t)(rowBlk + wave * 32 + srow) * 256 + skel;
  const bf16* gA1 = gA0 + (size_t)16 * 256;
  const bf16* gB0 = Bt + (size_t)(colBlk + wave * 32 + srow) * 256 + skel;
  const bf16* gB1 = gB0 + (size_t)16 * 256;
  bf16* const lA0 = As0 + wave * 32 * 32;
  bf16* const lA0b = As0 + (wave * 32 + 16) * 32;
  bf16* const lA1 = As1 + wave * 32 * 32;
  bf16* const lA1b = As1 + (wave * 32 + 16) * 32;
  bf16* const lB0 = Bs0 + wave * 32 * 32;
  bf16* const lB0b = Bs0 + (wave * 32 + 16) * 32;
  bf16* const lB1 = Bs1 + wave * 32 * 32;
  bf16* const lB1b = Bs1 + (wave * 32 + 16) * 32;

  f32x4 acc[4][4] = {};
  for (int k0 = 0; k0 < 256; k0 += 64) {
    gld_lds16(gA0 + k0, lA0);
    gld_lds16(gA1 + k0, lA0b);
    gld_lds16(gA0 + k0 + 32, lA1);
    gld_lds16(gA1 + k0 + 32, lA1b);
    gld_lds16(gB0 + k0, lB0);
    gld_lds16(gB1 + k0, lB0b);
    gld_lds16(gB0 + k0 + 32, lB1);
    gld_lds16(gB1 + k0 + 32, lB1b);
    __syncthreads();
#pragma unroll
    for (int ks = 0; ks < 2; ++ks) {
      const bf16* aRd = (ks ? As1 : As0) + (wr * 64 + l16) * 32 + quad * 8;
      const bf16* bRd = (ks ? Bs1 : Bs0) + (wc * 64 + l16) * 32 + quad * 8;
      bf16x8 af[4], bfr[4];
#pragma unroll
      for (int i = 0; i < 4; ++i) {
        af[i] = *(const bf16x8*)(aRd + i * 16 * 32);
        bfr[i] = *(const bf16x8*)(bRd + i * 16 * 32);
      }
#pragma unroll
      for (int mi = 0; mi < 4; ++mi)
#pragma unroll
        for (int ni = 0; ni < 4; ++ni)
          acc[mi][ni] = MFMA16(bfr[ni], af[mi], acc[mi][ni]);
    }
    __syncthreads();
  }

  const int seg = colBlk >> 10;  // 0: policy, 1: dyn-z (linear), 2: value
  bf16* const Cp = (seg == 0) ? Ha : (seg == 1) ? Hp : Hv;
  const int cShift = seg << 10;
  const float* const bp = (seg == 2) ? (vbiasT - 2048) : pdb1;
#pragma unroll
  for (int mi = 0; mi < 4; ++mi) {
    const int row = rowBlk + wr * 64 + mi * 16 + l16;
#pragma unroll
    for (int ni = 0; ni < 4; ++ni) {
      const int col0 = colBlk + wc * 64 + ni * 16 + quad * 4;
      const f32x4 bb = *(const f32x4*)(bp + col0);
      bf16x4 o;
#pragma unroll
      for (int r = 0; r < 4; ++r) {
        float x = acc[mi][ni][r] + bb[r];
        if (seg != 1) x = silu(x);
        o[r] = (bf16)x;
      }
      *(bf16x4*)(Cp + (size_t)row * 1024 + (col0 - cShift)) = o;
    }
  }
}

// ---- merged [policy-L2 | value-L2+dot] dispatch -----------------------
// grid (M/128, 16) row-major. y<8: silu(Ha@pW2+pb2)->Hc.
// y>=8: efe += disc * silu(Hv@vW2+vb2).vW3  (no C output).
__global__ __launch_bounds__(256) void gemm_pl2v(
    const bf16* __restrict__ Ha, const bf16* __restrict__ Hv,
    const bf16* __restrict__ pW2t, const bf16* __restrict__ vW2t,
    const float* __restrict__ pb2, const float* __restrict__ vb2,
    const float* __restrict__ vW3, bf16* __restrict__ Hc,
    float* __restrict__ efe, float disc) {
  __shared__ alignas(16) bf16 As0[128 * 32], As1[128 * 32];
  __shared__ alignas(16) bf16 Bs0[128 * 32], Bs1[128 * 32];
  const int tid = threadIdx.x, wave = tid >> 6, lane = tid & 63;
  const int quad = lane >> 4, l16 = lane & 15;
  const bool isV = (blockIdx.y >= 8);
  const int rowBlk = blockIdx.x * 128;
  const int colBlk = (isV ? blockIdx.y - 8 : blockIdx.y) * 128;
  const bf16* const A = isV ? Hv : Ha;
  const bf16* const Bt = isV ? vW2t : pW2t;
  const int wr = wave >> 1, wc = wave & 1;
  const int srow = lane >> 2, skel = (lane & 3) * 8;

  const bf16* gA0 = A + (size_t)(rowBlk + wave * 32 + srow) * 1024 + skel;
  const bf16* gA1 = gA0 + (size_t)16 * 1024;
  const bf16* gB0 = Bt + (size_t)(colBlk + wave * 32 + srow) * 1024 + skel;
  const bf16* gB1 = gB0 + (size_t)16 * 1024;
  bf16* const lA0 = As0 + wave * 32 * 32;
  bf16* const lA0b = As0 + (wave * 32 + 16) * 32;
  bf16* const lA1 = As1 + wave * 32 * 32;
  bf16* const lA1b = As1 + (wave * 32 + 16) * 32;
  bf16* const lB0 = Bs0 + wave * 32 * 32;
  bf16* const lB0b = Bs0 + (wave * 32 + 16) * 32;
  bf16* const lB1 = Bs1 + wave * 32 * 32;
  bf16* const lB1b = Bs1 + (wave * 32 + 16) * 32;

  f32x4 acc[4][4] = {};
  for (int k0 = 0; k0 < 1024; k0 += 64) {
    gld_lds16(gA0 + k0, lA0);
    gld_lds16(gA1 + k0, lA0b);
    gld_lds16(gA0 + k0 + 32, lA1);
    gld_lds16(gA1 + k0 + 32, lA1b);
    gld_lds16(gB0 + k0, lB0);
    gld_lds16(gB1 + k0, lB0b);
    gld_lds16(gB0 + k0 + 32, lB1);
    gld_lds16(gB1 + k0 + 32, lB1b);
    __syncthreads();
#pragma unroll
    for (int ks = 0; ks < 2; ++ks) {
      const bf16* aRd = (ks ? As1 : As0) + (wr * 64 + l16) * 32 + quad * 8;
      const bf16* bRd = (ks ? Bs1 : Bs0) + (wc * 64 + l16) * 32 + quad * 8;
      bf16x8 af[4], bfr[4];
#pragma unroll
      for (int i = 0; i < 4; ++i) {
        af[i] = *(const bf16x8*)(aRd + i * 16 * 32);
        bfr[i] = *(const bf16x8*)(bRd + i * 16 * 32);
      }
#pragma unroll
      for (int mi = 0; mi < 4; ++mi)
#pragma unroll
        for (int ni = 0; ni < 4; ++ni)
          acc[mi][ni] = MFMA16(bfr[ni], af[mi], acc[mi][ni]);
    }
    __syncthreads();
  }

  if (!isV) {
#pragma unroll
    for (int mi = 0; mi < 4; ++mi) {
      const int row = rowBlk + wr * 64 + mi * 16 + l16;
#pragma unroll
      for (int ni = 0; ni < 4; ++ni) {
        const int col0 = colBlk + wc * 64 + ni * 16 + quad * 4;
        const f32x4 bb = *(const f32x4*)(pb2 + col0);
        bf16x4 o;
#pragma unroll
        for (int r = 0; r < 4; ++r) o[r] = (bf16)silu(acc[mi][ni][r] + bb[r]);
        *(bf16x4*)(Hc + (size_t)row * 1024 + col0) = o;
      }
    }
  } else {
#pragma unroll
    for (int mi = 0; mi < 4; ++mi) {
      const int row = rowBlk + wr * 64 + mi * 16 + l16;
      float p = 0.f;
#pragma unroll
      for (int ni = 0; ni < 4; ++ni) {
        const int col0 = colBlk + wc * 64 + ni * 16 + quad * 4;
        const f32x4 bb = *(const f32x4*)(vb2 + col0);
        const f32x4 w3 = *(const f32x4*)(vW3 + col0);
#pragma unroll
        for (int r = 0; r < 4; ++r) p += silu(acc[mi][ni][r] + bb[r]) * w3[r];
      }
      p += __shfl_xor(p, 16);
      p += __shfl_xor(p, 32);
      if (quad == 0) atomicAdd(efe + row, disc * p);
    }
  }
}

// ---- standalone value L2 + vW3 dot (tail step) ------------------------
// grid (M/128, 8) row-major.
__global__ __launch_bounds__(256) void gemm_vdot(
    const bf16* __restrict__ A, const bf16* __restrict__ Bt,
    const float* __restrict__ vb2, const float* __restrict__ vW3,
    float* __restrict__ efe, float disc) {
  __shared__ alignas(16) bf16 As0[128 * 32], As1[128 * 32];
  __shared__ alignas(16) bf16 Bs0[128 * 32], Bs1[128 * 32];
  const int tid = threadIdx.x, wave = tid >> 6, lane = tid & 63;
  const int quad = lane >> 4, l16 = lane & 15;
  const int rowBlk = blockIdx.x * 128, colBlk = blockIdx.y * 128;
  const int wr = wave >> 1, wc = wave & 1;
  const int srow = lane >> 2, skel = (lane & 3) * 8;

  const bf16* gA0 = A + (size_t)(rowBlk + wave * 32 + srow) * 1024 + skel;
  const bf16* gA1 = gA0 + (size_t)16 * 1024;
  const bf16* gB0 = Bt + (size_t)(colBlk + wave * 32 + srow) * 1024 + skel;
  const bf16* gB1 = gB0 + (size_t)16 * 1024;
  bf16* const lA0 = As0 + wave * 32 * 32;
  bf16* const lA0b = As0 + (wave * 32 + 16) * 32;
  bf16* const lA1 = As1 + wave * 32 * 32;
  bf16* const lA1b = As1 + (wave * 32 + 16) * 32;
  bf16* const lB0 = Bs0 + wave * 32 * 32;
  bf16* const lB0b = Bs0 + (wave * 32 + 16) * 32;
  bf16* const lB1 = Bs1 + wave * 32 * 32;
  bf16* const lB1b = Bs1 + (wave * 32 + 16) * 32;

  f32x4 acc[4][4] = {};
  for (int k0 = 0; k0 < 1024; k0 += 64) {
    gld_lds16(gA0 + k0, lA0);
    gld_lds16(gA1 + k0, lA0b);
    gld_lds16(gA0 + k0 + 32, lA1);
    gld_lds16(gA1 + k0 + 32, lA1b);
    gld_lds16(gB0 + k0, lB0);
    gld_lds16(gB1 + k0, lB0b);
    gld_lds16(gB0 + k0 + 32, lB1);
    gld_lds16(gB1 + k0 + 32, lB1b);
    __syncthreads();
#pragma unroll
    for (int ks = 0; ks < 2; ++ks) {
      const bf16* aRd = (ks ? As1 : As0) + (wr * 64 + l16) * 32 + quad * 8;
      const bf16* bRd = (ks ? Bs1 : Bs0) + (wc * 64 + l16) * 32 + quad * 8;
      bf16x8 af[4], bfr[4];
#pragma unroll
      for (int i = 0; i < 4; ++i) {
        af[i] = *(const bf16x8*)(aRd + i * 16 * 32);
        bfr[i] = *(const bf16x8*)(bRd + i * 16 * 32);
      }
#pragma unroll
      for (int mi = 0; mi < 4; ++mi)
#pragma unroll
        for (int ni = 0; ni < 4; ++ni)
          acc[mi][ni] = MFMA16(bfr[ni], af[mi], acc[mi][ni]);
    }
    __syncthreads();
  }

#pragma unroll
  for (int mi = 0; mi < 4; ++mi) {
    const int row = rowBlk + wr * 64 + mi * 16 + l16;
    float p = 0.f;
#pragma unroll
    for (int ni = 0; ni < 4; ++ni) {
      const int col0 = colBlk + wc * 64 + ni * 16 + quad * 4;
      const f32x4 bb = *(const f32x4*)(vb2 + col0);
      const f32x4 w3 = *(const f32x4*)(vW3 + col0);
#pragma unroll
      for (int r = 0; r < 4; ++r) p += silu(acc[mi][ni][r] + bb[r]) * w3[r];
    }
    p += __shfl_xor(p, 16);
    p += __shfl_xor(p, 32);
    if (quad == 0) atomicAdd(efe + row, disc * p);
  }
}

// ---- dynamics L3 + z_next + KL partials fused -------------------------
// grid (M/64, 2), block 256: 64 rows x 128 cols per block, wave = 16 rows.
__global__ __launch_bounds__(256) void gemm_dyn3(
    const bf16* __restrict__ A, const bf16* __restrict__ Bt,
    const float* __restrict__ db3, float* __restrict__ Zf,
    bf16* __restrict__ Zb, float* __restrict__ s_n, float* __restrict__ s_c) {
  __shared__ alignas(16) bf16 As0[64 * 32], As1[64 * 32];
  __shared__ alignas(16) bf16 Bs0[128 * 32], Bs1[128 * 32];
  const int tid = threadIdx.x, wave = tid >> 6, lane = tid & 63;
  const int quad = lane >> 4, l16 = lane & 15;
  const int rowBlk = blockIdx.x * 64, colBlk = blockIdx.y * 128;
  const int srow = lane >> 2, skel = (lane & 3) * 8;

  const bf16* gA = A + (size_t)(rowBlk + wave * 16 + srow) * 1024 + skel;
  const bf16* gB0 = Bt + (size_t)(colBlk + wave * 32 + srow) * 1024 + skel;
  const bf16* gB1 = gB0 + (size_t)16 * 1024;
  bf16* const lA0 = As0 + wave * 16 * 32;
  bf16* const lA1 = As1 + wave * 16 * 32;
  bf16* const lB0 = Bs0 + wave * 32 * 32;
  bf16* const lB0b = Bs0 + (wave * 32 + 16) * 32;
  bf16* const lB1 = Bs1 + wave * 32 * 32;
  bf16* const lB1b = Bs1 + (wave * 32 + 16) * 32;

  f32x4 acc[8] = {};
  for (int k0 = 0; k0 < 1024; k0 += 64) {
    gld_lds16(gA + k0, lA0);
    gld_lds16(gA + k0 + 32, lA1);
    gld_lds16(gB0 + k0, lB0);
    gld_lds16(gB1 + k0, lB0b);
    gld_lds16(gB0 + k0 + 32, lB1);
    gld_lds16(gB1 + k0 + 32, lB1b);
    __syncthreads();
#pragma unroll
    for (int ks = 0; ks < 2; ++ks) {
      const bf16* aRd = (ks ? As1 : As0) + (wave * 16 + l16) * 32 + quad * 8;
      const bf16* bRd = (ks ? Bs1 : Bs0) + l16 * 32 + quad * 8;
      const bf16x8 af = *(const bf16x8*)aRd;
#pragma unroll
      for (int ni = 0; ni < 8; ++ni) {
        const bf16x8 bfr = *(const bf16x8*)(bRd + ni * 16 * 32);
        acc[ni] = MFMA16(bfr, af, acc[ni]);
      }
    }
    __syncthreads();
  }

  const int row = rowBlk + wave * 16 + l16;
  float pn = 0.f, pc = 0.f;
#pragma unroll
  for (int ni = 0; ni < 8; ++ni) {
    const int col0 = colBlk + ni * 16 + quad * 4;
    const f32x4 b4 = *(const f32x4*)(db3 + col0);
    float* zp = Zf + (size_t)row * 256 + col0;
    const f32x4 z = *(const f32x4*)zp;
    f32x4 zn;
    bf16x4 o;
#pragma unroll
    for (int r = 0; r < 4; ++r) {
      zn[r] = z[r] + acc[ni][r] + b4[r];
      pn += zn[r] * zn[r];
      pc += z[r] * zn[r];
      o[r] = (bf16)zn[r];
    }
    *(f32x4*)zp = zn;
    *(bf16x4*)(Zb + (size_t)row * 256 + col0) = o;
  }
  pn += __shfl_xor(pn, 16);
  pn += __shfl_xor(pn, 32);
  pc += __shfl_xor(pc, 16);
  pc += __shfl_xor(pc, 32);
  if (quad == 0) {
    atomicAdd(s_n + row, pn);
    atomicAdd(s_c + row, pc);
  }
}

// ---- batched KL epilogue: all 5 steps at once -------------------------
__global__ void kl_batch(const float* __restrict__ sz0,
                         const float* __restrict__ snAll,
                         const float* __restrict__ scAll,
                         float* __restrict__ efe) {
  const int m = blockIdx.x * 256 + threadIdx.x;
  float sz = sz0[m];
  float disc = 1.f, acc = 0.f;
  for (int t = 0; t < HORIZON; ++t) {
    const float sn = snAll[t * MR + m], sc = scAll[t * MR + m];
    const float nz = sqrtf(sz) + 1e-8f, nn = sqrtf(sn) + 1e-8f;
    const float kl =
        0.5f * (sz / (nz * nz) + sn / (nn * nn) - 2.f * sc / (nz * nn));
    acc += disc * log1pf(fmaxf(kl, 0.f));
    sz = sn;
    disc *= 0.99f;
  }
  efe[m] += acc;
}

// ---- heads + dynamics-L1 completion -----------------------------------
// grid (M/64), block 256. rmask: H/preD row mask (1023 at t=0, else ~0).
__global__ __launch_bounds__(256) void heads3(
    const bf16* __restrict__ H, const bf16* __restrict__ Wt,
    const float* __restrict__ pbm, const float* __restrict__ pbs,
    const float* __restrict__ noise, const bf16* __restrict__ preD,
    const bf16* __restrict__ dW1at, bf16* __restrict__ Hd,
    float* __restrict__ efe, int t, float disc, int rmask) {
  __shared__ alignas(16) bf16 As0[64 * 32], As1[64 * 32];
  __shared__ alignas(16) bf16 Bs0[64 * 32], Bs1[64 * 32];
  __shared__ alignas(16) bf16 LAct[64 * 32];
  const int tid = threadIdx.x, wave = tid >> 6, lane = tid & 63;
  const int quad = lane >> 4, l16 = lane & 15;
  const int rowBlk = blockIdx.x * 64;
  const int srow = lane >> 2, skel = (lane & 3) * 8;

  const bf16* gA =
      H + (size_t)((rowBlk + wave * 16 + srow) & rmask) * 1024 + skel;
  const bf16* gB = Wt + (size_t)(wave * 16 + srow) * 1024 + skel;
  bf16* const lA0 = As0 + wave * 16 * 32;
  bf16* const lA1 = As1 + wave * 16 * 32;
  bf16* const lB0 = Bs0 + wave * 16 * 32;
  bf16* const lB1 = Bs1 + wave * 16 * 32;

  f32x4 acc[4] = {};
  for (int k0 = 0; k0 < 1024; k0 += 64) {
    gld_lds16(gA + k0, lA0);
    gld_lds16(gA + k0 + 32, lA1);
    gld_lds16(gB + k0, lB0);
    gld_lds16(gB + k0 + 32, lB1);
    __syncthreads();
#pragma unroll
    for (int ks = 0; ks < 2; ++ks) {
      const bf16* aRd = (ks ? As1 : As0) + (wave * 16 + l16) * 32 + quad * 8;
      const bf16* bRd = (ks ? Bs1 : Bs0) + l16 * 32 + quad * 8;
      const bf16x8 af = *(const bf16x8*)aRd;
#pragma unroll
      for (int ni = 0; ni < 4; ++ni) {
        const bf16x8 bfr = *(const bf16x8*)(bRd + ni * 16 * 32);
        acc[ni] = MFMA16(bfr, af, acc[ni]);
      }
    }
    __syncthreads();
  }

  const int row = rowBlk + wave * 16 + l16;
  const int n = row >> 10, b = row & 1023;
  float ent = 0.f;
#pragma unroll
  for (int ni = 0; ni < 2; ++ni) {
    const int col0 = ni * 16 + quad * 4;
    const f32x4 bm4 = *(const f32x4*)(pbm + col0);
    const f32x4 bs4 = *(const f32x4*)(pbs + col0);
    const f32x4 ep4 =
        *(const f32x4*)(noise + (((size_t)(n * 5 + t) * 1024 + b) * 32 + col0));
    bf16x4 o;
#pragma unroll
    for (int r = 0; r < 4; ++r) {
      const float mean = acc[ni][r] + bm4[r];
      float ls = acc[ni + 2][r] + bs4[r];
      ls = fminf(fmaxf(ls, -5.f), 2.f);
      o[r] = (bf16)(mean + __expf(ls) * ep4[r]);
      ent += ENT_C + ls;
    }
    *(bf16x4*)(LAct + (wave * 16 + l16) * 32 + col0) = o;
  }
  ent += __shfl_xor(ent, 16);
  ent += __shfl_xor(ent, 32);
  if (quad == 0) efe[row] += disc * (-0.1f) * ent;
  __syncthreads();  // LAct ready

  // rank-32 completion: Hd[row][c] = silu(preD[row][c] + act[row,:]·dW1a[:,c])
  const int prow = row & rmask;
  const bf16x8 af2 = *(const bf16x8*)(LAct + (wave * 16 + l16) * 32 + quad * 8);
#pragma unroll 4
  for (int ct = 0; ct < 64; ++ct) {
    const bf16x8 wf =
        *(const bf16x8*)(dW1at + (size_t)(ct * 16 + l16) * 32 + quad * 8);
    f32x4 a = {};
    a = MFMA16(wf, af2, a);
    const int col0 = ct * 16 + quad * 4;
    const bf16x4 pd = *(const bf16x4*)(preD + (size_t)prow * 1024 + col0);
    bf16x4 o;
#pragma unroll
    for (int r = 0; r < 4; ++r) o[r] = (bf16)silu(a[r] + (float)pd[r]);
    *(bf16x4*)(Hd + (size_t)row * 1024 + col0) = o;
  }
}

// ---- mega weight-prep: all transposes/concats in one dispatch ---------
// segments (element counts):
//  s0 pdW1vt 3072*256 | s1 pW2t 1024*1024 | s2 pHt 64*1024 | s3 dW1at
//  1024*32 | s4 dW2t 1024*1024 | s5 dW3t 256*1024 | s6 vW2t 1024*1024 |
//  s7 pdb1 2048
__global__ void mega_prep(const float* __restrict__ pW1,
                          const float* __restrict__ dW1,
                          const float* __restrict__ vW1,
                          const float* __restrict__ pW2,
                          const float* __restrict__ dW2,
                          const float* __restrict__ dW3,
                          const float* __restrict__ vW2,
                          const float* __restrict__ pWm,
                          const float* __restrict__ pWs,
                          const float* __restrict__ pb1,
                          const float* __restrict__ db1,
                          bf16* __restrict__ pdW1vt, bf16* __restrict__ pW2t,
                          bf16* __restrict__ pHt, bf16* __restrict__ dW1at,
                          bf16* __restrict__ dW2t, bf16* __restrict__ dW3t,
                          bf16* __restrict__ vW2t, float* __restrict__ pdb1) {
  int idx = blockIdx.x * 256 + threadIdx.x;
  // s0: pdW1vt [3072][256]
  if (idx < 3072 * 256) {
    const int n = idx >> 8, k = idx & 255;
    float v;
    if (n < 1024) v = pW1[(size_t)k * 1024 + n];
    else if (n < 2048) v = dW1[(size_t)k * 1024 + (n - 1024)];
    else v = vW1[(size_t)k * 1024 + (n - 2048)];
    pdW1vt[idx] = (bf16)v;
    return;
  }
  idx -= 3072 * 256;
  // s1: pW2t [1024][1024]
  if (idx < 1024 * 1024) {
    const int n = idx >> 10, k = idx & 1023;
    pW2t[idx] = (bf16)pW2[(size_t)k * 1024 + n];
    return;
  }
  idx -= 1024 * 1024;
  // s2: pHt [64][1024]
  if (idx < 64 * 1024) {
    const int n = idx >> 10, k = idx & 1023;
    pHt[idx] = (bf16)((n < 32) ? pWm[k * 32 + n] : pWs[k * 32 + (n - 32)]);
    return;
  }
  idx -= 64 * 1024;
  // s3: dW1at [1024][32]
  if (idx < 1024 * 32) {
    const int n = idx >> 5, k = idx & 31;
    dW1at[idx] = (bf16)dW1[(size_t)(256 + k) * 1024 + n];
    return;
  }
  idx -= 1024 * 32;
  // s4: dW2t [1024][1024]
  if (idx < 1024 * 1024) {
    const int n = idx >> 10, k = idx & 1023;
    dW2t[idx] = (bf16)dW2[(size_t)k * 1024 + n];
    return;
  }
  idx -= 1024 * 1024;
  // s5: dW3t [256][1024]
  if (idx < 256 * 1024) {
    const int n = idx >> 10, k = idx & 1023;
    dW3t[idx] = (bf16)dW3[(size_t)k * 256 + n];
    return;
  }
  idx -= 256 * 1024;
  // s6: vW2t [1024][1024]
  if (idx < 1024 * 1024) {
    const int n = idx >> 10, k = idx & 1023;
    vW2t[idx] = (bf16)vW2[(size_t)k * 1024 + n];
    return;
  }
  idx -= 1024 * 1024;
  // s7: pdb1 [2048]
  if (idx < 2048) pdb1[idx] = (idx < 1024) ? pb1[idx] : db1[idx - 1024];
}

__global__ void make_vbias(const float* __restrict__ vW1,
                           const float* __restrict__ vb1,
                           float* __restrict__ vbias) {
  const int idx = blockIdx.x * 256 + threadIdx.x;
  if (idx >= 5 * 1024) return;
  const int t = idx >> 10, j = idx & 1023;
  float s = vb1[j];
  const float lt = (float)t;
  for (int i = 0; i < 64; ++i) {
    const float f = expf(-9.210340371976184f * (float)i / 64.f);
    const float ang = lt * f;
    s += sinf(ang) * vW1[(size_t)(256 + i) * 1024 + j];
    s += cosf(ang) * vW1[(size_t)(256 + 64 + i) * 1024 + j];
  }
  vbias[idx] = s;
}

// one block per row m: Zf replicated, Zb0 (first 1024 rows), sz0, zeros
__global__ void init_state3(const float* __restrict__ latent,
                            float* __restrict__ Zf, bf16* __restrict__ Zb0,
                            float* __restrict__ efe, float* __restrict__ sz0,
                            float* __restrict__ snAll,
                            float* __restrict__ scAll) {
  __shared__ float red[4];
  const int m = blockIdx.x, c = threadIdx.x;
  const float z = latent[(size_t)(m & 1023) * 256 + c];
  Zf[(size_t)m * 256 + c] = z;
  if (m < 1024) Zb0[(size_t)m * 256 + c] = (bf16)z;
  float v = z * z;
#pragma unroll
  for (int msk = 1; msk < 64; msk <<= 1) v += __shfl_xor(v, msk);
  if ((c & 63) == 0) red[c >> 6] = v;
  __syncthreads();
  if (c < HORIZON) {
    snAll[c * MR + m] = 0.f;
    scAll[c * MR + m] = 0.f;
  }
  if (c == 0) {
    sz0[m] = red[0] + red[1] + red[2] + red[3];
    efe[m] = 0.f;
  }
}

__global__ void finalize(const float* __restrict__ efe,
                         const float* __restrict__ vb3,
                         float* __restrict__ out) {
  const int b = blockIdx.x * 256 + threadIdx.x;  // 1024
  float s = 0.f;
#pragma unroll
  for (int n = 0; n < 16; ++n) s += efe[n * 1024 + b];
  out[b] = s * (1.f / 16.f) + SUMDISC * vb3[0];
}

extern "C" void kernel_launch(void* const* d_in, const int* in_sizes, int n_in,
                              void* d_out, int out_size, void* d_ws,
                              size_t ws_size, hipStream_t stream) {
  const float* latent = (const float*)d_in[0];
  const float* noise = (const float*)d_in[1];
  const float* pW1 = (const float*)d_in[2];
  const float* pb1 = (const float*)d_in[3];
  const float* pW2 = (const float*)d_in[4];
  const float* pb2 = (const float*)d_in[5];
  const float* pWm = (const float*)d_in[6];
  const float* pbm = (const float*)d_in[7];
  const float* pWs = (const float*)d_in[8];
  const float* pbs = (const float*)d_in[9];
  const float* dW1 = (const float*)d_in[10];
  const float* db1 = (const float*)d_in[11];
  const float* dW2 = (const float*)d_in[12];
  const float* db2 = (const float*)d_in[13];
  const float* dW3 = (const float*)d_in[14];
  const float* db3 = (const float*)d_in[15];
  const float* vW1 = (const float*)d_in[16];
  const float* vb1 = (const float*)d_in[17];
  const float* vW2 = (const float*)d_in[18];
  const float* vb2 = (const float*)d_in[19];
  const float* vW3 = (const float*)d_in[20];
  const float* vb3 = (const float*)d_in[21];

  char* w = (char*)d_ws;
  size_t off = 0;
  auto take = [&](size_t bytes) -> void* {
    void* p = (void*)(w + off);
    off = (off + bytes + 255) & ~(size_t)255;
    return p;
  };
  bf16* pdW1vt = (bf16*)take(3072ull * 256 * 2);  // [pW1|dW1z|vW1]^T
  float* pdb1 = (float*)take(2048ull * 4);
  bf16* pW2t = (bf16*)take(1024ull * 1024 * 2);
  bf16* pHt = (bf16*)take(64ull * 1024 * 2);
  bf16* dW1at = (bf16*)take(1024ull * 32 * 2);
  bf16* dW2t = (bf16*)take(1024ull * 1024 * 2);
  bf16* dW3t = (bf16*)take(256ull * 1024 * 2);
  bf16* vW2t = (bf16*)take(1024ull * 1024 * 2);
  float* vbias = (float*)take(5ull * 1024 * 4);
  bf16* Zb0 = (bf16*)take(1024ull * 256 * 2);      // z0 bf16, shared rows
  bf16* Zb = (bf16*)take((size_t)MR * 256 * 2);    // z_t bf16 (single buf)
  float* Zf = (float*)take((size_t)MR * 256 * 4);  // fp32 master z
  float* efe = (float*)take((size_t)MR * 4);
  float* sz0 = (float*)take((size_t)MR * 4);
  float* snAll = (float*)take(5ull * MR * 4);
  float* scAll = (float*)take(5ull * MR * 4);
  bf16* Ha = (bf16*)take((size_t)MR * 1024 * 2);
  bf16* Hc = (bf16*)take((size_t)MR * 1024 * 2);
  bf16* Hp = (bf16*)take((size_t)MR * 1024 * 2);
  bf16* Hv = (bf16*)take((size_t)MR * 1024 * 2);
  bf16* vW1t = pdW1vt + (size_t)2048 * 256;  // value-L1 weights (tail step)

  const dim3 blk(256);
  const int BIG = 1 << 30;
  const int PREP_N = 3072 * 256 + 3 * 1024 * 1024 + 64 * 1024 + 1024 * 32 +
                     256 * 1024 + 2048;
  mega_prep<<<dim3((PREP_N + 255) / 256), blk, 0, stream>>>(
      pW1, dW1, vW1, pW2, dW2, dW3, vW2, pWm, pWs, pb1, db1, pdW1vt, pW2t, pHt,
      dW1at, dW2t, dW3t, vW2t, pdb1);
  make_vbias<<<dim3(20), blk, 0, stream>>>(vW1, vb1, vbias);
  init_state3<<<dim3(MR), blk, 0, stream>>>(latent, Zf, Zb0, efe, sz0, snAll,
                                            scAll);

  float disc = 1.f, dprev = 1.f;
  for (int s = 0; s < HORIZON; ++s) {
    const int rmask = (s == 0) ? 1023 : 0x7FFFFFFF;
    if (s == 0) {
      // [policy L1 | dyn L1z] only: M=1024 (shared latent), N=2048
      gemm128<<<dim3(8, 16), blk, 0, stream>>>(Zb0, 256, 256, pdW1vt, pdb1,
                                               1024, Ha, Hp, 1024);
      // policy L2 at M=1024
      gemm128<<<dim3(8, 8), blk, 0, stream>>>(Ha, 1024, 1024, pW2t, pb2, BIG,
                                              Hc, Hc, 1024);
    } else {
      // trunk + value-L1 for pragmatic(s-1) on z_s: N=3072
      gemm_pd1v<<<dim3(128, 24), blk, 0, stream>>>(
          Zb, pdW1vt, pdb1, vbias + (s - 1) * 1024, Ha, Hp, Hv);
      // merged [policy L2 | value L2 + vW3 dot]
      gemm_pl2v<<<dim3(128, 16), blk, 0, stream>>>(Ha, Hv, pW2t, vW2t, pb2,
                                                   vb2, vW3, Hc, efe, dprev);
    }
    // heads + dyn-L1 completion: Hc,Hp (masked rows) -> action/ent, Hd -> Ha
    heads3<<<dim3(MR / 64), blk, 0, stream>>>(Hc, pHt, pbm, pbs, noise, Hp,
                                              dW1at, Ha, efe, s, disc, rmask);
    // dynamics L2: Ha -> Hc
    gemm128<<<dim3(128, 8), blk, 0, stream>>>(Ha, 1024, 1024, dW2t, db2, BIG,
                                              Hc, Hc, 1024);
    // dynamics L3 fused with z_next / KL partials; writes Zb = z_{s+1}
    gemm_dyn3<<<dim3(MR / 64, 2), blk, 0, stream>>>(
        Hc, dW3t, db3, Zf, Zb, snAll + (size_t)s * MR, scAll + (size_t)s * MR);
    dprev = disc;
    disc *= 0.99f;
  }

  kl_batch<<<dim3(MR / 256), blk, 0, stream>>>(sz0, snAll, scAll, efe);

  // final pragmatic(4) on z_5: value L1 then L2+dot
  gemm128<<<dim3(128, 8), blk, 0, stream>>>(Zb, 256, 256, vW1t,
                                            vbias + 4 * 1024, BIG, Hv, Hv,
                                            1024);
  gemm_vdot<<<dim3(128, 8), blk, 0, stream>>>(Hv, vW2t, vb2, vW3, efe, dprev);
  finalize<<<dim3(4), blk, 0, stream>>>(efe, vb3, (float*)d_out);
}

// Round 7
// 1498.546 us; speedup vs baseline: 1.1923x; 1.1923x over previous
//
#include <hip/hip_runtime.h>
#include <cstdint>
#include <cstddef>
#include <cmath>

// DiffusionActiveInference on MI355X (gfx950).
// R7: revert R6's pl2v merge (VGPR 144 -> occupancy collapse + both weight
// matrices thrashing one XCD L2). Separate gemm128(pL2) + gemm_vdot, both
// row-major grid (x=row -> XCD affinity, R3-validated). Keep mega_prep,
// pd1v trunk fusion, dyn3 fusion, batched KL, t=0 specialization.

typedef __bf16 bf16;
typedef __attribute__((ext_vector_type(8))) __bf16 bf16x8;
typedef __attribute__((ext_vector_type(4))) __bf16 bf16x4;
typedef __attribute__((ext_vector_type(4))) float f32x4;

static constexpr int BATCH = 1024, NTRAJ = 16, HORIZON = 5;
static constexpr int MR = NTRAJ * BATCH;  // 16384 GEMM rows
static constexpr float ENT_C = 1.4189385332046727f;  // 0.5*(1+log(2*pi))
static constexpr float SUMDISC = 4.90099501f;        // sum 0.99^t, t=0..4

// ---- async global->LDS, 16B per lane ----------------------------------
__device__ __forceinline__ void gld_lds16(const bf16* g, const bf16* l) {
  typedef __attribute__((address_space(1))) const uint32_t gq_t;
  typedef __attribute__((address_space(3))) uint32_t lq_t;
  gq_t* gp = (gq_t*)(uintptr_t)g;
  lq_t* lp = (lq_t*)(uint32_t)(uintptr_t)l;
  __builtin_amdgcn_global_load_lds(gp, lp, 16, 0, 0);
}

__device__ __forceinline__ float silu(float x) {
  return x / (1.f + __expf(-x));
}

#define MFMA16(a, b, c) __builtin_amdgcn_mfma_f32_16x16x32_bf16((a), (b), (c), 0, 0, 0)

// ---- generic GEMM: C = maybe_silu(A[M,K](lda) @ Bt[N,K]^T + bias) -----
// grid (M/128, N/128) ROW-major (x=row -> XCD affinity). BK=64 dual panels.
// silu iff colBlk < act_cols; out to C1 else C2 at (col - act_cols).
__global__ __launch_bounds__(256) void gemm128(
    const bf16* __restrict__ A, int lda, int K, const bf16* __restrict__ Bt,
    const float* __restrict__ bias, int act_cols,
    bf16* __restrict__ C1, bf16* __restrict__ C2, int ldc) {
  __shared__ alignas(16) bf16 As0[128 * 32], As1[128 * 32];
  __shared__ alignas(16) bf16 Bs0[128 * 32], Bs1[128 * 32];
  const int tid = threadIdx.x, wave = tid >> 6, lane = tid & 63;
  const int quad = lane >> 4, l16 = lane & 15;
  const int rowBlk = blockIdx.x * 128, colBlk = blockIdx.y * 128;
  const int wr = wave >> 1, wc = wave & 1;
  const int srow = lane >> 2, skel = (lane & 3) * 8;

  const bf16* gA0 = A + (size_t)(rowBlk + wave * 32 + srow) * lda + skel;
  const bf16* gA1 = gA0 + (size_t)16 * lda;
  const bf16* gB0 = Bt + (size_t)(colBlk + wave * 32 + srow) * K + skel;
  const bf16* gB1 = gB0 + (size_t)16 * K;
  bf16* const lA0 = As0 + wave * 32 * 32;
  bf16* const lA0b = As0 + (wave * 32 + 16) * 32;
  bf16* const lA1 = As1 + wave * 32 * 32;
  bf16* const lA1b = As1 + (wave * 32 + 16) * 32;
  bf16* const lB0 = Bs0 + wave * 32 * 32;
  bf16* const lB0b = Bs0 + (wave * 32 + 16) * 32;
  bf16* const lB1 = Bs1 + wave * 32 * 32;
  bf16* const lB1b = Bs1 + (wave * 32 + 16) * 32;

  f32x4 acc[4][4] = {};
  for (int k0 = 0; k0 < K; k0 += 64) {
    gld_lds16(gA0 + k0, lA0);
    gld_lds16(gA1 + k0, lA0b);
    gld_lds16(gA0 + k0 + 32, lA1);
    gld_lds16(gA1 + k0 + 32, lA1b);
    gld_lds16(gB0 + k0, lB0);
    gld_lds16(gB1 + k0, lB0b);
    gld_lds16(gB0 + k0 + 32, lB1);
    gld_lds16(gB1 + k0 + 32, lB1b);
    __syncthreads();
#pragma unroll
    for (int ks = 0; ks < 2; ++ks) {
      const bf16* aRd = (ks ? As1 : As0) + (wr * 64 + l16) * 32 + quad * 8;
      const bf16* bRd = (ks ? Bs1 : Bs0) + (wc * 64 + l16) * 32 + quad * 8;
      bf16x8 af[4], bfr[4];
#pragma unroll
      for (int i = 0; i < 4; ++i) {
        af[i] = *(const bf16x8*)(aRd + i * 16 * 32);
        bfr[i] = *(const bf16x8*)(bRd + i * 16 * 32);
      }
#pragma unroll
      for (int mi = 0; mi < 4; ++mi)
#pragma unroll
        for (int ni = 0; ni < 4; ++ni)
          acc[mi][ni] = MFMA16(bfr[ni], af[mi], acc[mi][ni]);
    }
    __syncthreads();
  }

  const bool doAct = (colBlk < act_cols);
  bf16* const Cp = doAct ? C1 : C2;
  const int cShift = doAct ? 0 : act_cols;
#pragma unroll
  for (int mi = 0; mi < 4; ++mi) {
    const int row = rowBlk + wr * 64 + mi * 16 + l16;
#pragma unroll
    for (int ni = 0; ni < 4; ++ni) {
      const int col0 = colBlk + wc * 64 + ni * 16 + quad * 4;
      const f32x4 bb = *(const f32x4*)(bias + col0);
      bf16x4 o;
#pragma unroll
      for (int r = 0; r < 4; ++r) {
        float x = acc[mi][ni][r] + bb[r];
        if (doAct) x = silu(x);
        o[r] = (bf16)x;
      }
      *(bf16x4*)(Cp + (size_t)row * ldc + (col0 - cShift)) = o;
    }
  }
}

// ---- per-step trunk: [policy-L1 | dyn-L1z | value-L1] in one GEMM -----
// grid (M/128, 24) row-major. K=256. Cols 0..1023 silu->Ha; 1024..2047
// linear->Hp; 2048..3071 silu(+vbias[t-1])->Hv.
__global__ __launch_bounds__(256) void gemm_pd1v(
    const bf16* __restrict__ A, const bf16* __restrict__ Bt,
    const float* __restrict__ pdb1, const float* __restrict__ vbiasT,
    bf16* __restrict__ Ha, bf16* __restrict__ Hp, bf16* __restrict__ Hv) {
  __shared__ alignas(16) bf16 As0[128 * 32], As1[128 * 32];
  __shared__ alignas(16) bf16 Bs0[128 * 32], Bs1[128 * 32];
  const int tid = threadIdx.x, wave = tid >> 6, lane = tid & 63;
  const int quad = lane >> 4, l16 = lane & 15;
  const int rowBlk = blockIdx.x * 128, colBlk = blockIdx.y * 128;
  const int wr = wave >> 1, wc = wave & 1;
  const int srow = lane >> 2, skel = (lane & 3) * 8;

  const bf16* gA0 = A + (size_t)(rowBlk + wave * 32 + srow) * 256 + skel;
  const bf16* gA1 = gA0 + (size_t)16 * 256;
  const bf16* gB0 = Bt + (size_t)(colBlk + wave * 32 + srow) * 256 + skel;
  const bf16* gB1 = gB0 + (size_t)16 * 256;
  bf16* const lA0 = As0 + wave * 32 * 32;
  bf16* const lA0b = As0 + (wave * 32 + 16) * 32;
  bf16* const lA1 = As1 + wave * 32 * 32;
  bf16* const lA1b = As1 + (wave * 32 + 16) * 32;
  bf16* const lB0 = Bs0 + wave * 32 * 32;
  bf16* const lB0b = Bs0 + (wave * 32 + 16) * 32;
  bf16* const lB1 = Bs1 + wave * 32 * 32;
  bf16* const lB1b = Bs1 + (wave * 32 + 16) * 32;

  f32x4 acc[4][4] = {};
  for (int k0 = 0; k0 < 256; k0 += 64) {
    gld_lds16(gA0 + k0, lA0);
    gld_lds16(gA1 + k0, lA0b);
    gld_lds16(gA0 + k0 + 32, lA1);
    gld_lds16(gA1 + k0 + 32, lA1b);
    gld_lds16(gB0 + k0, lB0);
    gld_lds16(gB1 + k0, lB0b);
    gld_lds16(gB0 + k0 + 32, lB1);
    gld_lds16(gB1 + k0 + 32, lB1b);
    __syncthreads();
#pragma unroll
    for (int ks = 0; ks < 2; ++ks) {
      const bf16* aRd = (ks ? As1 : As0) + (wr * 64 + l16) * 32 + quad * 8;
      const bf16* bRd = (ks ? Bs1 : Bs0) + (wc * 64 + l16) * 32 + quad * 8;
      bf16x8 af[4], bfr[4];
#pragma unroll
      for (int i = 0; i < 4; ++i) {
        af[i] = *(const bf16x8*)(aRd + i * 16 * 32);
        bfr[i] = *(const bf16x8*)(bRd + i * 16 * 32);
      }
#pragma unroll
      for (int mi = 0; mi < 4; ++mi)
#pragma unroll
        for (int ni = 0; ni < 4; ++ni)
          acc[mi][ni] = MFMA16(bfr[ni], af[mi], acc[mi][ni]);
    }
    __syncthreads();
  }

  const int seg = colBlk >> 10;  // 0: policy, 1: dyn-z (linear), 2: value
  bf16* const Cp = (seg == 0) ? Ha : (seg == 1) ? Hp : Hv;
  const int cShift = seg << 10;
  const float* const bp = (seg == 2) ? (vbiasT - 2048) : pdb1;
#pragma unroll
  for (int mi = 0; mi < 4; ++mi) {
    const int row = rowBlk + wr * 64 + mi * 16 + l16;
#pragma unroll
    for (int ni = 0; ni < 4; ++ni) {
      const int col0 = colBlk + wc * 64 + ni * 16 + quad * 4;
      const f32x4 bb = *(const f32x4*)(bp + col0);
      bf16x4 o;
#pragma unroll
      for (int r = 0; r < 4; ++r) {
        float x = acc[mi][ni][r] + bb[r];
        if (seg != 1) x = silu(x);
        o[r] = (bf16)x;
      }
      *(bf16x4*)(Cp + (size_t)row * 1024 + (col0 - cShift)) = o;
    }
  }
}

// ---- value L2 + vW3 dot fused: efe += disc * silu(A@vW2+vb2).vW3 ------
// grid (M/128, 8) row-major. No C output.
__global__ __launch_bounds__(256) void gemm_vdot(
    const bf16* __restrict__ A, const bf16* __restrict__ Bt,
    const float* __restrict__ vb2, const float* __restrict__ vW3,
    float* __restrict__ efe, float disc) {
  __shared__ alignas(16) bf16 As0[128 * 32], As1[128 * 32];
  __shared__ alignas(16) bf16 Bs0[128 * 32], Bs1[128 * 32];
  const int tid = threadIdx.x, wave = tid >> 6, lane = tid & 63;
  const int quad = lane >> 4, l16 = lane & 15;
  const int rowBlk = blockIdx.x * 128, colBlk = blockIdx.y * 128;
  const int wr = wave >> 1, wc = wave & 1;
  const int srow = lane >> 2, skel = (lane & 3) * 8;

  const bf16* gA0 = A + (size_t)(rowBlk + wave * 32 + srow) * 1024 + skel;
  const bf16* gA1 = gA0 + (size_t)16 * 1024;
  const bf16* gB0 = Bt + (size_t)(colBlk + wave * 32 + srow) * 1024 + skel;
  const bf16* gB1 = gB0 + (size_t)16 * 1024;
  bf16* const lA0 = As0 + wave * 32 * 32;
  bf16* const lA0b = As0 + (wave * 32 + 16) * 32;
  bf16* const lA1 = As1 + wave * 32 * 32;
  bf16* const lA1b = As1 + (wave * 32 + 16) * 32;
  bf16* const lB0 = Bs0 + wave * 32 * 32;
  bf16* const lB0b = Bs0 + (wave * 32 + 16) * 32;
  bf16* const lB1 = Bs1 + wave * 32 * 32;
  bf16* const lB1b = Bs1 + (wave * 32 + 16) * 32;

  f32x4 acc[4][4] = {};
  for (int k0 = 0; k0 < 1024; k0 += 64) {
    gld_lds16(gA0 + k0, lA0);
    gld_lds16(gA1 + k0, lA0b);
    gld_lds16(gA0 + k0 + 32, lA1);
    gld_lds16(gA1 + k0 + 32, lA1b);
    gld_lds16(gB0 + k0, lB0);
    gld_lds16(gB1 + k0, lB0b);
    gld_lds16(gB0 + k0 + 32, lB1);
    gld_lds16(gB1 + k0 + 32, lB1b);
    __syncthreads();
#pragma unroll
    for (int ks = 0; ks < 2; ++ks) {
      const bf16* aRd = (ks ? As1 : As0) + (wr * 64 + l16) * 32 + quad * 8;
      const bf16* bRd = (ks ? Bs1 : Bs0) + (wc * 64 + l16) * 32 + quad * 8;
      bf16x8 af[4], bfr[4];
#pragma unroll
      for (int i = 0; i < 4; ++i) {
        af[i] = *(const bf16x8*)(aRd + i * 16 * 32);
        bfr[i] = *(const bf16x8*)(bRd + i * 16 * 32);
      }
#pragma unroll
      for (int mi = 0; mi < 4; ++mi)
#pragma unroll
        for (int ni = 0; ni < 4; ++ni)
          acc[mi][ni] = MFMA16(bfr[ni], af[mi], acc[mi][ni]);
    }
    __syncthreads();
  }

#pragma unroll
  for (int mi = 0; mi < 4; ++mi) {
    const int row = rowBlk + wr * 64 + mi * 16 + l16;
    float p = 0.f;
#pragma unroll
    for (int ni = 0; ni < 4; ++ni) {
      const int col0 = colBlk + wc * 64 + ni * 16 + quad * 4;
      const f32x4 bb = *(const f32x4*)(vb2 + col0);
      const f32x4 w3 = *(const f32x4*)(vW3 + col0);
#pragma unroll
      for (int r = 0; r < 4; ++r) p += silu(acc[mi][ni][r] + bb[r]) * w3[r];
    }
    p += __shfl_xor(p, 16);
    p += __shfl_xor(p, 32);
    if (quad == 0) atomicAdd(efe + row, disc * p);
  }
}

// ---- dynamics L3 + z_next + KL partials fused -------------------------
// grid (M/64, 2), block 256: 64 rows x 128 cols per block, wave = 16 rows.
__global__ __launch_bounds__(256) void gemm_dyn3(
    const bf16* __restrict__ A, const bf16* __restrict__ Bt,
    const float* __restrict__ db3, float* __restrict__ Zf,
    bf16* __restrict__ Zb, float* __restrict__ s_n, float* __restrict__ s_c) {
  __shared__ alignas(16) bf16 As0[64 * 32], As1[64 * 32];
  __shared__ alignas(16) bf16 Bs0[128 * 32], Bs1[128 * 32];
  const int tid = threadIdx.x, wave = tid >> 6, lane = tid & 63;
  const int quad = lane >> 4, l16 = lane & 15;
  const int rowBlk = blockIdx.x * 64, colBlk = blockIdx.y * 128;
  const int srow = lane >> 2, skel = (lane & 3) * 8;

  const bf16* gA = A + (size_t)(rowBlk + wave * 16 + srow) * 1024 + skel;
  const bf16* gB0 = Bt + (size_t)(colBlk + wave * 32 + srow) * 1024 + skel;
  const bf16* gB1 = gB0 + (size_t)16 * 1024;
  bf16* const lA0 = As0 + wave * 16 * 32;
  bf16* const lA1 = As1 + wave * 16 * 32;
  bf16* const lB0 = Bs0 + wave * 32 * 32;
  bf16* const lB0b = Bs0 + (wave * 32 + 16) * 32;
  bf16* const lB1 = Bs1 + wave * 32 * 32;
  bf16* const lB1b = Bs1 + (wave * 32 + 16) * 32;

  f32x4 acc[8] = {};
  for (int k0 = 0; k0 < 1024; k0 += 64) {
    gld_lds16(gA + k0, lA0);
    gld_lds16(gA + k0 + 32, lA1);
    gld_lds16(gB0 + k0, lB0);
    gld_lds16(gB1 + k0, lB0b);
    gld_lds16(gB0 + k0 + 32, lB1);
    gld_lds16(gB1 + k0 + 32, lB1b);
    __syncthreads();
#pragma unroll
    for (int ks = 0; ks < 2; ++ks) {
      const bf16* aRd = (ks ? As1 : As0) + (wave * 16 + l16) * 32 + quad * 8;
      const bf16* bRd = (ks ? Bs1 : Bs0) + l16 * 32 + quad * 8;
      const bf16x8 af = *(const bf16x8*)aRd;
#pragma unroll
      for (int ni = 0; ni < 8; ++ni) {
        const bf16x8 bfr = *(const bf16x8*)(bRd + ni * 16 * 32);
        acc[ni] = MFMA16(bfr, af, acc[ni]);
      }
    }
    __syncthreads();
  }

  const int row = rowBlk + wave * 16 + l16;
  float pn = 0.f, pc = 0.f;
#pragma unroll
  for (int ni = 0; ni < 8; ++ni) {
    const int col0 = colBlk + ni * 16 + quad * 4;
    const f32x4 b4 = *(const f32x4*)(db3 + col0);
    float* zp = Zf + (size_t)row * 256 + col0;
    const f32x4 z = *(const f32x4*)zp;
    f32x4 zn;
    bf16x4 o;
#pragma unroll
    for (int r = 0; r < 4; ++r) {
      zn[r] = z[r] + acc[ni][r] + b4[r];
      pn += zn[r] * zn[r];
      pc += z[r] * zn[r];
      o[r] = (bf16)zn[r];
    }
    *(f32x4*)zp = zn;
    *(bf16x4*)(Zb + (size_t)row * 256 + col0) = o;
  }
  pn += __shfl_xor(pn, 16);
  pn += __shfl_xor(pn, 32);
  pc += __shfl_xor(pc, 16);
  pc += __shfl_xor(pc, 32);
  if (quad == 0) {
    atomicAdd(s_n + row, pn);
    atomicAdd(s_c + row, pc);
  }
}

// ---- batched KL epilogue: all 5 steps at once -------------------------
__global__ void kl_batch(const float* __restrict__ sz0,
                         const float* __restrict__ snAll,
                         const float* __restrict__ scAll,
                         float* __restrict__ efe) {
  const int m = blockIdx.x * 256 + threadIdx.x;
  float sz = sz0[m];
  float disc = 1.f, acc = 0.f;
  for (int t = 0; t < HORIZON; ++t) {
    const float sn = snAll[t * MR + m], sc = scAll[t * MR + m];
    const float nz = sqrtf(sz) + 1e-8f, nn = sqrtf(sn) + 1e-8f;
    const float kl =
        0.5f * (sz / (nz * nz) + sn / (nn * nn) - 2.f * sc / (nz * nn));
    acc += disc * log1pf(fmaxf(kl, 0.f));
    sz = sn;
    disc *= 0.99f;
  }
  efe[m] += acc;
}

// ---- heads + dynamics-L1 completion -----------------------------------
// grid (M/64), block 256. rmask: H/preD row mask (1023 at t=0, else ~0).
__global__ __launch_bounds__(256) void heads3(
    const bf16* __restrict__ H, const bf16* __restrict__ Wt,
    const float* __restrict__ pbm, const float* __restrict__ pbs,
    const float* __restrict__ noise, const bf16* __restrict__ preD,
    const bf16* __restrict__ dW1at, bf16* __restrict__ Hd,
    float* __restrict__ efe, int t, float disc, int rmask) {
  __shared__ alignas(16) bf16 As0[64 * 32], As1[64 * 32];
  __shared__ alignas(16) bf16 Bs0[64 * 32], Bs1[64 * 32];
  __shared__ alignas(16) bf16 LAct[64 * 32];
  const int tid = threadIdx.x, wave = tid >> 6, lane = tid & 63;
  const int quad = lane >> 4, l16 = lane & 15;
  const int rowBlk = blockIdx.x * 64;
  const int srow = lane >> 2, skel = (lane & 3) * 8;

  const bf16* gA =
      H + (size_t)((rowBlk + wave * 16 + srow) & rmask) * 1024 + skel;
  const bf16* gB = Wt + (size_t)(wave * 16 + srow) * 1024 + skel;
  bf16* const lA0 = As0 + wave * 16 * 32;
  bf16* const lA1 = As1 + wave * 16 * 32;
  bf16* const lB0 = Bs0 + wave * 16 * 32;
  bf16* const lB1 = Bs1 + wave * 16 * 32;

  f32x4 acc[4] = {};
  for (int k0 = 0; k0 < 1024; k0 += 64) {
    gld_lds16(gA + k0, lA0);
    gld_lds16(gA + k0 + 32, lA1);
    gld_lds16(gB + k0, lB0);
    gld_lds16(gB + k0 + 32, lB1);
    __syncthreads();
#pragma unroll
    for (int ks = 0; ks < 2; ++ks) {
      const bf16* aRd = (ks ? As1 : As0) + (wave * 16 + l16) * 32 + quad * 8;
      const bf16* bRd = (ks ? Bs1 : Bs0) + l16 * 32 + quad * 8;
      const bf16x8 af = *(const bf16x8*)aRd;
#pragma unroll
      for (int ni = 0; ni < 4; ++ni) {
        const bf16x8 bfr = *(const bf16x8*)(bRd + ni * 16 * 32);
        acc[ni] = MFMA16(bfr, af, acc[ni]);
      }
    }
    __syncthreads();
  }

  const int row = rowBlk + wave * 16 + l16;
  const int n = row >> 10, b = row & 1023;
  float ent = 0.f;
#pragma unroll
  for (int ni = 0; ni < 2; ++ni) {
    const int col0 = ni * 16 + quad * 4;
    const f32x4 bm4 = *(const f32x4*)(pbm + col0);
    const f32x4 bs4 = *(const f32x4*)(pbs + col0);
    const f32x4 ep4 =
        *(const f32x4*)(noise + (((size_t)(n * 5 + t) * 1024 + b) * 32 + col0));
    bf16x4 o;
#pragma unroll
    for (int r = 0; r < 4; ++r) {
      const float mean = acc[ni][r] + bm4[r];
      float ls = acc[ni + 2][r] + bs4[r];
      ls = fminf(fmaxf(ls, -5.f), 2.f);
      o[r] = (bf16)(mean + __expf(ls) * ep4[r]);
      ent += ENT_C + ls;
    }
    *(bf16x4*)(LAct + (wave * 16 + l16) * 32 + col0) = o;
  }
  ent += __shfl_xor(ent, 16);
  ent += __shfl_xor(ent, 32);
  if (quad == 0) efe[row] += disc * (-0.1f) * ent;
  __syncthreads();  // LAct ready

  // rank-32 completion: Hd[row][c] = silu(preD[row][c] + act[row,:]·dW1a[:,c])
  const int prow = row & rmask;
  const bf16x8 af2 = *(const bf16x8*)(LAct + (wave * 16 + l16) * 32 + quad * 8);
#pragma unroll 4
  for (int ct = 0; ct < 64; ++ct) {
    const bf16x8 wf =
        *(const bf16x8*)(dW1at + (size_t)(ct * 16 + l16) * 32 + quad * 8);
    f32x4 a = {};
    a = MFMA16(wf, af2, a);
    const int col0 = ct * 16 + quad * 4;
    const bf16x4 pd = *(const bf16x4*)(preD + (size_t)prow * 1024 + col0);
    bf16x4 o;
#pragma unroll
    for (int r = 0; r < 4; ++r) o[r] = (bf16)silu(a[r] + (float)pd[r]);
    *(bf16x4*)(Hd + (size_t)row * 1024 + col0) = o;
  }
}

// ---- mega weight-prep: all transposes/concats in one dispatch ---------
__global__ void mega_prep(const float* __restrict__ pW1,
                          const float* __restrict__ dW1,
                          const float* __restrict__ vW1,
                          const float* __restrict__ pW2,
                          const float* __restrict__ dW2,
                          const float* __restrict__ dW3,
                          const float* __restrict__ vW2,
                          const float* __restrict__ pWm,
                          const float* __restrict__ pWs,
                          const float* __restrict__ pb1,
                          const float* __restrict__ db1,
                          bf16* __restrict__ pdW1vt, bf16* __restrict__ pW2t,
                          bf16* __restrict__ pHt, bf16* __restrict__ dW1at,
                          bf16* __restrict__ dW2t, bf16* __restrict__ dW3t,
                          bf16* __restrict__ vW2t, float* __restrict__ pdb1) {
  int idx = blockIdx.x * 256 + threadIdx.x;
  if (idx < 3072 * 256) {
    const int n = idx >> 8, k = idx & 255;
    float v;
    if (n < 1024) v = pW1[(size_t)k * 1024 + n];
    else if (n < 2048) v = dW1[(size_t)k * 1024 + (n - 1024)];
    else v = vW1[(size_t)k * 1024 + (n - 2048)];
    pdW1vt[idx] = (bf16)v;
    return;
  }
  idx -= 3072 * 256;
  if (idx < 1024 * 1024) {
    const int n = idx >> 10, k = idx & 1023;
    pW2t[idx] = (bf16)pW2[(size_t)k * 1024 + n];
    return;
  }
  idx -= 1024 * 1024;
  if (idx < 64 * 1024) {
    const int n = idx >> 10, k = idx & 1023;
    pHt[idx] = (bf16)((n < 32) ? pWm[k * 32 + n] : pWs[k * 32 + (n - 32)]);
    return;
  }
  idx -= 64 * 1024;
  if (idx < 1024 * 32) {
    const int n = idx >> 5, k = idx & 31;
    dW1at[idx] = (bf16)dW1[(size_t)(256 + k) * 1024 + n];
    return;
  }
  idx -= 1024 * 32;
  if (idx < 1024 * 1024) {
    const int n = idx >> 10, k = idx & 1023;
    dW2t[idx] = (bf16)dW2[(size_t)k * 1024 + n];
    return;
  }
  idx -= 1024 * 1024;
  if (idx < 256 * 1024) {
    const int n = idx >> 10, k = idx & 1023;
    dW3t[idx] = (bf16)dW3[(size_t)k * 256 + n];
    return;
  }
  idx -= 256 * 1024;
  if (idx < 1024 * 1024) {
    const int n = idx >> 10, k = idx & 1023;
    vW2t[idx] = (bf16)vW2[(size_t)k * 1024 + n];
    return;
  }
  idx -= 1024 * 1024;
  if (idx < 2048) pdb1[idx] = (idx < 1024) ? pb1[idx] : db1[idx - 1024];
}

__global__ void make_vbias(const float* __restrict__ vW1,
                           const float* __restrict__ vb1,
                           float* __restrict__ vbias) {
  const int idx = blockIdx.x * 256 + threadIdx.x;
  if (idx >= 5 * 1024) return;
  const int t = idx >> 10, j = idx & 1023;
  float s = vb1[j];
  const float lt = (float)t;
  for (int i = 0; i < 64; ++i) {
    const float f = expf(-9.210340371976184f * (float)i / 64.f);
    const float ang = lt * f;
    s += sinf(ang) * vW1[(size_t)(256 + i) * 1024 + j];
    s += cosf(ang) * vW1[(size_t)(256 + 64 + i) * 1024 + j];
  }
  vbias[idx] = s;
}

// one block per row m: Zf replicated, Zb0 (first 1024 rows), sz0, zeros
__global__ void init_state3(const float* __restrict__ latent,
                            float* __restrict__ Zf, bf16* __restrict__ Zb0,
                            float* __restrict__ efe, float* __restrict__ sz0,
                            float* __restrict__ snAll,
                            float* __restrict__ scAll) {
  __shared__ float red[4];
  const int m = blockIdx.x, c = threadIdx.x;
  const float z = latent[(size_t)(m & 1023) * 256 + c];
  Zf[(size_t)m * 256 + c] = z;
  if (m < 1024) Zb0[(size_t)m * 256 + c] = (bf16)z;
  float v = z * z;
#pragma unroll
  for (int msk = 1; msk < 64; msk <<= 1) v += __shfl_xor(v, msk);
  if ((c & 63) == 0) red[c >> 6] = v;
  __syncthreads();
  if (c < HORIZON) {
    snAll[c * MR + m] = 0.f;
    scAll[c * MR + m] = 0.f;
  }
  if (c == 0) {
    sz0[m] = red[0] + red[1] + red[2] + red[3];
    efe[m] = 0.f;
  }
}

__global__ void finalize(const float* __restrict__ efe,
                         const float* __restrict__ vb3,
                         float* __restrict__ out) {
  const int b = blockIdx.x * 256 + threadIdx.x;  // 1024
  float s = 0.f;
#pragma unroll
  for (int n = 0; n < 16; ++n) s += efe[n * 1024 + b];
  out[b] = s * (1.f / 16.f) + SUMDISC * vb3[0];
}

extern "C" void kernel_launch(void* const* d_in, const int* in_sizes, int n_in,
                              void* d_out, int out_size, void* d_ws,
                              size_t ws_size, hipStream_t stream) {
  const float* latent = (const float*)d_in[0];
  const float* noise = (const float*)d_in[1];
  const float* pW1 = (const float*)d_in[2];
  const float* pb1 = (const float*)d_in[3];
  const float* pW2 = (const float*)d_in[4];
  const float* pb2 = (const float*)d_in[5];
  const float* pWm = (const float*)d_in[6];
  const float* pbm = (const float*)d_in[7];
  const float* pWs = (const float*)d_in[8];
  const float* pbs = (const float*)d_in[9];
  const float* dW1 = (const float*)d_in[10];
  const float* db1 = (const float*)d_in[11];
  const float* dW2 = (const float*)d_in[12];
  const float* db2 = (const float*)d_in[13];
  const float* dW3 = (const float*)d_in[14];
  const float* db3 = (const float*)d_in[15];
  const float* vW1 = (const float*)d_in[16];
  const float* vb1 = (const float*)d_in[17];
  const float* vW2 = (const float*)d_in[18];
  const float* vb2 = (const float*)d_in[19];
  const float* vW3 = (const float*)d_in[20];
  const float* vb3 = (const float*)d_in[21];

  char* w = (char*)d_ws;
  size_t off = 0;
  auto take = [&](size_t bytes) -> void* {
    void* p = (void*)(w + off);
    off = (off + bytes + 255) & ~(size_t)255;
    return p;
  };
  bf16* pdW1vt = (bf16*)take(3072ull * 256 * 2);  // [pW1|dW1z|vW1]^T
  float* pdb1 = (float*)take(2048ull * 4);
  bf16* pW2t = (bf16*)take(1024ull * 1024 * 2);
  bf16* pHt = (bf16*)take(64ull * 1024 * 2);
  bf16* dW1at = (bf16*)take(1024ull * 32 * 2);
  bf16* dW2t = (bf16*)take(1024ull * 1024 * 2);
  bf16* dW3t = (bf16*)take(256ull * 1024 * 2);
  bf16* vW2t = (bf16*)take(1024ull * 1024 * 2);
  float* vbias = (float*)take(5ull * 1024 * 4);
  bf16* Zb0 = (bf16*)take(1024ull * 256 * 2);      // z0 bf16, shared rows
  bf16* Zb = (bf16*)take((size_t)MR * 256 * 2);    // z_t bf16 (single buf)
  float* Zf = (float*)take((size_t)MR * 256 * 4);  // fp32 master z
  float* efe = (float*)take((size_t)MR * 4);
  float* sz0 = (float*)take((size_t)MR * 4);
  float* snAll = (float*)take(5ull * MR * 4);
  float* scAll = (float*)take(5ull * MR * 4);
  bf16* Ha = (bf16*)take((size_t)MR * 1024 * 2);
  bf16* Hc = (bf16*)take((size_t)MR * 1024 * 2);
  bf16* Hp = (bf16*)take((size_t)MR * 1024 * 2);
  bf16* Hv = (bf16*)take((size_t)MR * 1024 * 2);
  bf16* vW1t = pdW1vt + (size_t)2048 * 256;  // value-L1 weights (tail step)

  const dim3 blk(256);
  const int BIG = 1 << 30;
  const int PREP_N = 3072 * 256 + 3 * 1024 * 1024 + 64 * 1024 + 1024 * 32 +
                     256 * 1024 + 2048;
  mega_prep<<<dim3((PREP_N + 255) / 256), blk, 0, stream>>>(
      pW1, dW1, vW1, pW2, dW2, dW3, vW2, pWm, pWs, pb1, db1, pdW1vt, pW2t, pHt,
      dW1at, dW2t, dW3t, vW2t, pdb1);
  make_vbias<<<dim3(20), blk, 0, stream>>>(vW1, vb1, vbias);
  init_state3<<<dim3(MR), blk, 0, stream>>>(latent, Zf, Zb0, efe, sz0, snAll,
                                            scAll);

  float disc = 1.f, dprev = 1.f;
  for (int s = 0; s < HORIZON; ++s) {
    const int rmask = (s == 0) ? 1023 : 0x7FFFFFFF;
    if (s == 0) {
      // [policy L1 | dyn L1z] only: M=1024 (shared latent), N=2048
      gemm128<<<dim3(8, 16), blk, 0, stream>>>(Zb0, 256, 256, pdW1vt, pdb1,
                                               1024, Ha, Hp, 1024);
      // policy L2 at M=1024
      gemm128<<<dim3(8, 8), blk, 0, stream>>>(Ha, 1024, 1024, pW2t, pb2, BIG,
                                              Hc, Hc, 1024);
    } else {
      // trunk + value-L1 for pragmatic(s-1) on z_s: N=3072
      gemm_pd1v<<<dim3(128, 24), blk, 0, stream>>>(
          Zb, pdW1vt, pdb1, vbias + (s - 1) * 1024, Ha, Hp, Hv);
      // policy L2
      gemm128<<<dim3(128, 8), blk, 0, stream>>>(Ha, 1024, 1024, pW2t, pb2, BIG,
                                                Hc, Hc, 1024);
      // value L2 + vW3 dot -> efe (pragmatic of step s-1)
      gemm_vdot<<<dim3(128, 8), blk, 0, stream>>>(Hv, vW2t, vb2, vW3, efe,
                                                  dprev);
    }
    // heads + dyn-L1 completion: Hc,Hp (masked rows) -> action/ent, Hd -> Ha
    heads3<<<dim3(MR / 64), blk, 0, stream>>>(Hc, pHt, pbm, pbs, noise, Hp,
                                              dW1at, Ha, efe, s, disc, rmask);
    // dynamics L2: Ha -> Hc
    gemm128<<<dim3(128, 8), blk, 0, stream>>>(Ha, 1024, 1024, dW2t, db2, BIG,
                                              Hc, Hc, 1024);
    // dynamics L3 fused with z_next / KL partials; writes Zb = z_{s+1}
    gemm_dyn3<<<dim3(MR / 64, 2), blk, 0, stream>>>(
        Hc, dW3t, db3, Zf, Zb, snAll + (size_t)s * MR, scAll + (size_t)s * MR);
    dprev = disc;
    disc *= 0.99f;
  }

  kl_batch<<<dim3(MR / 256), blk, 0, stream>>>(sz0, snAll, scAll, efe);

  // final pragmatic(4) on z_5: value L1 then L2+dot
  gemm128<<<dim3(128, 8), blk, 0, stream>>>(Zb, 256, 256, vW1t,
                                            vbias + 4 * 1024, BIG, Hv, Hv,
                                            1024);
  gemm_vdot<<<dim3(128, 8), blk, 0, stream>>>(Hv, vW2t, vb2, vW3, efe, dprev);
  finalize<<<dim3(4), blk, 0, stream>>>(efe, vb3, (float*)d_out);
}

// Round 8
// 1457.831 us; speedup vs baseline: 1.2256x; 1.0279x over previous
//
#include <hip/hip_runtime.h>
#include <cstdint>
#include <cstddef>
#include <cmath>

// DiffusionActiveInference on MI355X (gfx950).
// R8: single prep_tr dispatch replaces mega_prep/make_vbias/init_state3:
// LDS-tiled coalesced transposes (mega_prep's reads were stride-4KB
// uncoalesced), vbias + wave-per-row init folded in as block ranges.
// All compute kernels byte-identical to R7 (1498 us best).

typedef __bf16 bf16;
typedef __attribute__((ext_vector_type(8))) __bf16 bf16x8;
typedef __attribute__((ext_vector_type(4))) __bf16 bf16x4;
typedef __attribute__((ext_vector_type(4))) float f32x4;

static constexpr int BATCH = 1024, NTRAJ = 16, HORIZON = 5;
static constexpr int MR = NTRAJ * BATCH;  // 16384 GEMM rows
static constexpr float ENT_C = 1.4189385332046727f;  // 0.5*(1+log(2*pi))
static constexpr float SUMDISC = 4.90099501f;        // sum 0.99^t, t=0..4

// ---- async global->LDS, 16B per lane ----------------------------------
__device__ __forceinline__ void gld_lds16(const bf16* g, const bf16* l) {
  typedef __attribute__((address_space(1))) const uint32_t gq_t;
  typedef __attribute__((address_space(3))) uint32_t lq_t;
  gq_t* gp = (gq_t*)(uintptr_t)g;
  lq_t* lp = (lq_t*)(uint32_t)(uintptr_t)l;
  __builtin_amdgcn_global_load_lds(gp, lp, 16, 0, 0);
}

__device__ __forceinline__ float silu(float x) {
  return x / (1.f + __expf(-x));
}

#define MFMA16(a, b, c) __builtin_amdgcn_mfma_f32_16x16x32_bf16((a), (b), (c), 0, 0, 0)

// ---- generic GEMM: C = maybe_silu(A[M,K](lda) @ Bt[N,K]^T + bias) -----
// grid (M/128, N/128) ROW-major (x=row -> XCD affinity). BK=64 dual panels.
// silu iff colBlk < act_cols; out to C1 else C2 at (col - act_cols).
__global__ __launch_bounds__(256) void gemm128(
    const bf16* __restrict__ A, int lda, int K, const bf16* __restrict__ Bt,
    const float* __restrict__ bias, int act_cols,
    bf16* __restrict__ C1, bf16* __restrict__ C2, int ldc) {
  __shared__ alignas(16) bf16 As0[128 * 32], As1[128 * 32];
  __shared__ alignas(16) bf16 Bs0[128 * 32], Bs1[128 * 32];
  const int tid = threadIdx.x, wave = tid >> 6, lane = tid & 63;
  const int quad = lane >> 4, l16 = lane & 15;
  const int rowBlk = blockIdx.x * 128, colBlk = blockIdx.y * 128;
  const int wr = wave >> 1, wc = wave & 1;
  const int srow = lane >> 2, skel = (lane & 3) * 8;

  const bf16* gA0 = A + (size_t)(rowBlk + wave * 32 + srow) * lda + skel;
  const bf16* gA1 = gA0 + (size_t)16 * lda;
  const bf16* gB0 = Bt + (size_t)(colBlk + wave * 32 + srow) * K + skel;
  const bf16* gB1 = gB0 + (size_t)16 * K;
  bf16* const lA0 = As0 + wave * 32 * 32;
  bf16* const lA0b = As0 + (wave * 32 + 16) * 32;
  bf16* const lA1 = As1 + wave * 32 * 32;
  bf16* const lA1b = As1 + (wave * 32 + 16) * 32;
  bf16* const lB0 = Bs0 + wave * 32 * 32;
  bf16* const lB0b = Bs0 + (wave * 32 + 16) * 32;
  bf16* const lB1 = Bs1 + wave * 32 * 32;
  bf16* const lB1b = Bs1 + (wave * 32 + 16) * 32;

  f32x4 acc[4][4] = {};
  for (int k0 = 0; k0 < K; k0 += 64) {
    gld_lds16(gA0 + k0, lA0);
    gld_lds16(gA1 + k0, lA0b);
    gld_lds16(gA0 + k0 + 32, lA1);
    gld_lds16(gA1 + k0 + 32, lA1b);
    gld_lds16(gB0 + k0, lB0);
    gld_lds16(gB1 + k0, lB0b);
    gld_lds16(gB0 + k0 + 32, lB1);
    gld_lds16(gB1 + k0 + 32, lB1b);
    __syncthreads();
#pragma unroll
    for (int ks = 0; ks < 2; ++ks) {
      const bf16* aRd = (ks ? As1 : As0) + (wr * 64 + l16) * 32 + quad * 8;
      const bf16* bRd = (ks ? Bs1 : Bs0) + (wc * 64 + l16) * 32 + quad * 8;
      bf16x8 af[4], bfr[4];
#pragma unroll
      for (int i = 0; i < 4; ++i) {
        af[i] = *(const bf16x8*)(aRd + i * 16 * 32);
        bfr[i] = *(const bf16x8*)(bRd + i * 16 * 32);
      }
#pragma unroll
      for (int mi = 0; mi < 4; ++mi)
#pragma unroll
        for (int ni = 0; ni < 4; ++ni)
          acc[mi][ni] = MFMA16(bfr[ni], af[mi], acc[mi][ni]);
    }
    __syncthreads();
  }

  const bool doAct = (colBlk < act_cols);
  bf16* const Cp = doAct ? C1 : C2;
  const int cShift = doAct ? 0 : act_cols;
#pragma unroll
  for (int mi = 0; mi < 4; ++mi) {
    const int row = rowBlk + wr * 64 + mi * 16 + l16;
#pragma unroll
    for (int ni = 0; ni < 4; ++ni) {
      const int col0 = colBlk + wc * 64 + ni * 16 + quad * 4;
      const f32x4 bb = *(const f32x4*)(bias + col0);
      bf16x4 o;
#pragma unroll
      for (int r = 0; r < 4; ++r) {
        float x = acc[mi][ni][r] + bb[r];
        if (doAct) x = silu(x);
        o[r] = (bf16)x;
      }
      *(bf16x4*)(Cp + (size_t)row * ldc + (col0 - cShift)) = o;
    }
  }
}

// ---- per-step trunk: [policy-L1 | dyn-L1z | value-L1] in one GEMM -----
// grid (M/128, 24) row-major. K=256. Cols 0..1023 silu->Ha; 1024..2047
// linear->Hp; 2048..3071 silu(+vbias[t-1])->Hv.
__global__ __launch_bounds__(256) void gemm_pd1v(
    const bf16* __restrict__ A, const bf16* __restrict__ Bt,
    const float* __restrict__ pdb1, const float* __restrict__ vbiasT,
    bf16* __restrict__ Ha, bf16* __restrict__ Hp, bf16* __restrict__ Hv) {
  __shared__ alignas(16) bf16 As0[128 * 32], As1[128 * 32];
  __shared__ alignas(16) bf16 Bs0[128 * 32], Bs1[128 * 32];
  const int tid = threadIdx.x, wave = tid >> 6, lane = tid & 63;
  const int quad = lane >> 4, l16 = lane & 15;
  const int rowBlk = blockIdx.x * 128, colBlk = blockIdx.y * 128;
  const int wr = wave >> 1, wc = wave & 1;
  const int srow = lane >> 2, skel = (lane & 3) * 8;

  const bf16* gA0 = A + (size_t)(rowBlk + wave * 32 + srow) * 256 + skel;
  const bf16* gA1 = gA0 + (size_t)16 * 256;
  const bf16* gB0 = Bt + (size_t)(colBlk + wave * 32 + srow) * 256 + skel;
  const bf16* gB1 = gB0 + (size_t)16 * 256;
  bf16* const lA0 = As0 + wave * 32 * 32;
  bf16* const lA0b = As0 + (wave * 32 + 16) * 32;
  bf16* const lA1 = As1 + wave * 32 * 32;
  bf16* const lA1b = As1 + (wave * 32 + 16) * 32;
  bf16* const lB0 = Bs0 + wave * 32 * 32;
  bf16* const lB0b = Bs0 + (wave * 32 + 16) * 32;
  bf16* const lB1 = Bs1 + wave * 32 * 32;
  bf16* const lB1b = Bs1 + (wave * 32 + 16) * 32;

  f32x4 acc[4][4] = {};
  for (int k0 = 0; k0 < 256; k0 += 64) {
    gld_lds16(gA0 + k0, lA0);
    gld_lds16(gA1 + k0, lA0b);
    gld_lds16(gA0 + k0 + 32, lA1);
    gld_lds16(gA1 + k0 + 32, lA1b);
    gld_lds16(gB0 + k0, lB0);
    gld_lds16(gB1 + k0, lB0b);
    gld_lds16(gB0 + k0 + 32, lB1);
    gld_lds16(gB1 + k0 + 32, lB1b);
    __syncthreads();
#pragma unroll
    for (int ks = 0; ks < 2; ++ks) {
      const bf16* aRd = (ks ? As1 : As0) + (wr * 64 + l16) * 32 + quad * 8;
      const bf16* bRd = (ks ? Bs1 : Bs0) + (wc * 64 + l16) * 32 + quad * 8;
      bf16x8 af[4], bfr[4];
#pragma unroll
      for (int i = 0; i < 4; ++i) {
        af[i] = *(const bf16x8*)(aRd + i * 16 * 32);
        bfr[i] = *(const bf16x8*)(bRd + i * 16 * 32);
      }
#pragma unroll
      for (int mi = 0; mi < 4; ++mi)
#pragma unroll
        for (int ni = 0; ni < 4; ++ni)
          acc[mi][ni] = MFMA16(bfr[ni], af[mi], acc[mi][ni]);
    }
    __syncthreads();
  }

  const int seg = colBlk >> 10;  // 0: policy, 1: dyn-z (linear), 2: value
  bf16* const Cp = (seg == 0) ? Ha : (seg == 1) ? Hp : Hv;
  const int cShift = seg << 10;
  const float* const bp = (seg == 2) ? (vbiasT - 2048) : pdb1;
#pragma unroll
  for (int mi = 0; mi < 4; ++mi) {
    const int row = rowBlk + wr * 64 + mi * 16 + l16;
#pragma unroll
    for (int ni = 0; ni < 4; ++ni) {
      const int col0 = colBlk + wc * 64 + ni * 16 + quad * 4;
      const f32x4 bb = *(const f32x4*)(bp + col0);
      bf16x4 o;
#pragma unroll
      for (int r = 0; r < 4; ++r) {
        float x = acc[mi][ni][r] + bb[r];
        if (seg != 1) x = silu(x);
        o[r] = (bf16)x;
      }
      *(bf16x4*)(Cp + (size_t)row * 1024 + (col0 - cShift)) = o;
    }
  }
}

// ---- value L2 + vW3 dot fused: efe += disc * silu(A@vW2+vb2).vW3 ------
// grid (M/128, 8) row-major. No C output.
__global__ __launch_bounds__(256) void gemm_vdot(
    const bf16* __restrict__ A, const bf16* __restrict__ Bt,
    const float* __restrict__ vb2, const float* __restrict__ vW3,
    float* __restrict__ efe, float disc) {
  __shared__ alignas(16) bf16 As0[128 * 32], As1[128 * 32];
  __shared__ alignas(16) bf16 Bs0[128 * 32], Bs1[128 * 32];
  const int tid = threadIdx.x, wave = tid >> 6, lane = tid & 63;
  const int quad = lane >> 4, l16 = lane & 15;
  const int rowBlk = blockIdx.x * 128, colBlk = blockIdx.y * 128;
  const int wr = wave >> 1, wc = wave & 1;
  const int srow = lane >> 2, skel = (lane & 3) * 8;

  const bf16* gA0 = A + (size_t)(rowBlk + wave * 32 + srow) * 1024 + skel;
  const bf16* gA1 = gA0 + (size_t)16 * 1024;
  const bf16* gB0 = Bt + (size_t)(colBlk + wave * 32 + srow) * 1024 + skel;
  const bf16* gB1 = gB0 + (size_t)16 * 1024;
  bf16* const lA0 = As0 + wave * 32 * 32;
  bf16* const lA0b = As0 + (wave * 32 + 16) * 32;
  bf16* const lA1 = As1 + wave * 32 * 32;
  bf16* const lA1b = As1 + (wave * 32 + 16) * 32;
  bf16* const lB0 = Bs0 + wave * 32 * 32;
  bf16* const lB0b = Bs0 + (wave * 32 + 16) * 32;
  bf16* const lB1 = Bs1 + wave * 32 * 32;
  bf16* const lB1b = Bs1 + (wave * 32 + 16) * 32;

  f32x4 acc[4][4] = {};
  for (int k0 = 0; k0 < 1024; k0 += 64) {
    gld_lds16(gA0 + k0, lA0);
    gld_lds16(gA1 + k0, lA0b);
    gld_lds16(gA0 + k0 + 32, lA1);
    gld_lds16(gA1 + k0 + 32, lA1b);
    gld_lds16(gB0 + k0, lB0);
    gld_lds16(gB1 + k0, lB0b);
    gld_lds16(gB0 + k0 + 32, lB1);
    gld_lds16(gB1 + k0 + 32, lB1b);
    __syncthreads();
#pragma unroll
    for (int ks = 0; ks < 2; ++ks) {
      const bf16* aRd = (ks ? As1 : As0) + (wr * 64 + l16) * 32 + quad * 8;
      const bf16* bRd = (ks ? Bs1 : Bs0) + (wc * 64 + l16) * 32 + quad * 8;
      bf16x8 af[4], bfr[4];
#pragma unroll
      for (int i = 0; i < 4; ++i) {
        af[i] = *(const bf16x8*)(aRd + i * 16 * 32);
        bfr[i] = *(const bf16x8*)(bRd + i * 16 * 32);
      }
#pragma unroll
      for (int mi = 0; mi < 4; ++mi)
#pragma unroll
        for (int ni = 0; ni < 4; ++ni)
          acc[mi][ni] = MFMA16(bfr[ni], af[mi], acc[mi][ni]);
    }
    __syncthreads();
  }

#pragma unroll
  for (int mi = 0; mi < 4; ++mi) {
    const int row = rowBlk + wr * 64 + mi * 16 + l16;
    float p = 0.f;
#pragma unroll
    for (int ni = 0; ni < 4; ++ni) {
      const int col0 = colBlk + wc * 64 + ni * 16 + quad * 4;
      const f32x4 bb = *(const f32x4*)(vb2 + col0);
      const f32x4 w3 = *(const f32x4*)(vW3 + col0);
#pragma unroll
      for (int r = 0; r < 4; ++r) p += silu(acc[mi][ni][r] + bb[r]) * w3[r];
    }
    p += __shfl_xor(p, 16);
    p += __shfl_xor(p, 32);
    if (quad == 0) atomicAdd(efe + row, disc * p);
  }
}

// ---- dynamics L3 + z_next + KL partials fused -------------------------
// grid (M/64, 2), block 256: 64 rows x 128 cols per block, wave = 16 rows.
__global__ __launch_bounds__(256) void gemm_dyn3(
    const bf16* __restrict__ A, const bf16* __restrict__ Bt,
    const float* __restrict__ db3, float* __restrict__ Zf,
    bf16* __restrict__ Zb, float* __restrict__ s_n, float* __restrict__ s_c) {
  __shared__ alignas(16) bf16 As0[64 * 32], As1[64 * 32];
  __shared__ alignas(16) bf16 Bs0[128 * 32], Bs1[128 * 32];
  const int tid = threadIdx.x, wave = tid >> 6, lane = tid & 63;
  const int quad = lane >> 4, l16 = lane & 15;
  const int rowBlk = blockIdx.x * 64, colBlk = blockIdx.y * 128;
  const int srow = lane >> 2, skel = (lane & 3) * 8;

  const bf16* gA = A + (size_t)(rowBlk + wave * 16 + srow) * 1024 + skel;
  const bf16* gB0 = Bt + (size_t)(colBlk + wave * 32 + srow) * 1024 + skel;
  const bf16* gB1 = gB0 + (size_t)16 * 1024;
  bf16* const lA0 = As0 + wave * 16 * 32;
  bf16* const lA1 = As1 + wave * 16 * 32;
  bf16* const lB0 = Bs0 + wave * 32 * 32;
  bf16* const lB0b = Bs0 + (wave * 32 + 16) * 32;
  bf16* const lB1 = Bs1 + wave * 32 * 32;
  bf16* const lB1b = Bs1 + (wave * 32 + 16) * 32;

  f32x4 acc[8] = {};
  for (int k0 = 0; k0 < 1024; k0 += 64) {
    gld_lds16(gA + k0, lA0);
    gld_lds16(gA + k0 + 32, lA1);
    gld_lds16(gB0 + k0, lB0);
    gld_lds16(gB1 + k0, lB0b);
    gld_lds16(gB0 + k0 + 32, lB1);
    gld_lds16(gB1 + k0 + 32, lB1b);
    __syncthreads();
#pragma unroll
    for (int ks = 0; ks < 2; ++ks) {
      const bf16* aRd = (ks ? As1 : As0) + (wave * 16 + l16) * 32 + quad * 8;
      const bf16* bRd = (ks ? Bs1 : Bs0) + l16 * 32 + quad * 8;
      const bf16x8 af = *(const bf16x8*)aRd;
#pragma unroll
      for (int ni = 0; ni < 8; ++ni) {
        const bf16x8 bfr = *(const bf16x8*)(bRd + ni * 16 * 32);
        acc[ni] = MFMA16(bfr, af, acc[ni]);
      }
    }
    __syncthreads();
  }

  const int row = rowBlk + wave * 16 + l16;
  float pn = 0.f, pc = 0.f;
#pragma unroll
  for (int ni = 0; ni < 8; ++ni) {
    const int col0 = colBlk + ni * 16 + quad * 4;
    const f32x4 b4 = *(const f32x4*)(db3 + col0);
    float* zp = Zf + (size_t)row * 256 + col0;
    const f32x4 z = *(const f32x4*)zp;
    f32x4 zn;
    bf16x4 o;
#pragma unroll
    for (int r = 0; r < 4; ++r) {
      zn[r] = z[r] + acc[ni][r] + b4[r];
      pn += zn[r] * zn[r];
      pc += z[r] * zn[r];
      o[r] = (bf16)zn[r];
    }
    *(f32x4*)zp = zn;
    *(bf16x4*)(Zb + (size_t)row * 256 + col0) = o;
  }
  pn += __shfl_xor(pn, 16);
  pn += __shfl_xor(pn, 32);
  pc += __shfl_xor(pc, 16);
  pc += __shfl_xor(pc, 32);
  if (quad == 0) {
    atomicAdd(s_n + row, pn);
    atomicAdd(s_c + row, pc);
  }
}

// ---- batched KL epilogue: all 5 steps at once -------------------------
__global__ void kl_batch(const float* __restrict__ sz0,
                         const float* __restrict__ snAll,
                         const float* __restrict__ scAll,
                         float* __restrict__ efe) {
  const int m = blockIdx.x * 256 + threadIdx.x;
  float sz = sz0[m];
  float disc = 1.f, acc = 0.f;
  for (int t = 0; t < HORIZON; ++t) {
    const float sn = snAll[t * MR + m], sc = scAll[t * MR + m];
    const float nz = sqrtf(sz) + 1e-8f, nn = sqrtf(sn) + 1e-8f;
    const float kl =
        0.5f * (sz / (nz * nz) + sn / (nn * nn) - 2.f * sc / (nz * nn));
    acc += disc * log1pf(fmaxf(kl, 0.f));
    sz = sn;
    disc *= 0.99f;
  }
  efe[m] += acc;
}

// ---- heads + dynamics-L1 completion -----------------------------------
// grid (M/64), block 256. rmask: H/preD row mask (1023 at t=0, else ~0).
__global__ __launch_bounds__(256) void heads3(
    const bf16* __restrict__ H, const bf16* __restrict__ Wt,
    const float* __restrict__ pbm, const float* __restrict__ pbs,
    const float* __restrict__ noise, const bf16* __restrict__ preD,
    const bf16* __restrict__ dW1at, bf16* __restrict__ Hd,
    float* __restrict__ efe, int t, float disc, int rmask) {
  __shared__ alignas(16) bf16 As0[64 * 32], As1[64 * 32];
  __shared__ alignas(16) bf16 Bs0[64 * 32], Bs1[64 * 32];
  __shared__ alignas(16) bf16 LAct[64 * 32];
  const int tid = threadIdx.x, wave = tid >> 6, lane = tid & 63;
  const int quad = lane >> 4, l16 = lane & 15;
  const int rowBlk = blockIdx.x * 64;
  const int srow = lane >> 2, skel = (lane & 3) * 8;

  const bf16* gA =
      H + (size_t)((rowBlk + wave * 16 + srow) & rmask) * 1024 + skel;
  const bf16* gB = Wt + (size_t)(wave * 16 + srow) * 1024 + skel;
  bf16* const lA0 = As0 + wave * 16 * 32;
  bf16* const lA1 = As1 + wave * 16 * 32;
  bf16* const lB0 = Bs0 + wave * 16 * 32;
  bf16* const lB1 = Bs1 + wave * 16 * 32;

  f32x4 acc[4] = {};
  for (int k0 = 0; k0 < 1024; k0 += 64) {
    gld_lds16(gA + k0, lA0);
    gld_lds16(gA + k0 + 32, lA1);
    gld_lds16(gB + k0, lB0);
    gld_lds16(gB + k0 + 32, lB1);
    __syncthreads();
#pragma unroll
    for (int ks = 0; ks < 2; ++ks) {
      const bf16* aRd = (ks ? As1 : As0) + (wave * 16 + l16) * 32 + quad * 8;
      const bf16* bRd = (ks ? Bs1 : Bs0) + l16 * 32 + quad * 8;
      const bf16x8 af = *(const bf16x8*)aRd;
#pragma unroll
      for (int ni = 0; ni < 4; ++ni) {
        const bf16x8 bfr = *(const bf16x8*)(bRd + ni * 16 * 32);
        acc[ni] = MFMA16(bfr, af, acc[ni]);
      }
    }
    __syncthreads();
  }

  const int row = rowBlk + wave * 16 + l16;
  const int n = row >> 10, b = row & 1023;
  float ent = 0.f;
#pragma unroll
  for (int ni = 0; ni < 2; ++ni) {
    const int col0 = ni * 16 + quad * 4;
    const f32x4 bm4 = *(const f32x4*)(pbm + col0);
    const f32x4 bs4 = *(const f32x4*)(pbs + col0);
    const f32x4 ep4 =
        *(const f32x4*)(noise + (((size_t)(n * 5 + t) * 1024 + b) * 32 + col0));
    bf16x4 o;
#pragma unroll
    for (int r = 0; r < 4; ++r) {
      const float mean = acc[ni][r] + bm4[r];
      float ls = acc[ni + 2][r] + bs4[r];
      ls = fminf(fmaxf(ls, -5.f), 2.f);
      o[r] = (bf16)(mean + __expf(ls) * ep4[r]);
      ent += ENT_C + ls;
    }
    *(bf16x4*)(LAct + (wave * 16 + l16) * 32 + col0) = o;
  }
  ent += __shfl_xor(ent, 16);
  ent += __shfl_xor(ent, 32);
  if (quad == 0) efe[row] += disc * (-0.1f) * ent;
  __syncthreads();  // LAct ready

  // rank-32 completion: Hd[row][c] = silu(preD[row][c] + act[row,:]·dW1a[:,c])
  const int prow = row & rmask;
  const bf16x8 af2 = *(const bf16x8*)(LAct + (wave * 16 + l16) * 32 + quad * 8);
#pragma unroll 4
  for (int ct = 0; ct < 64; ++ct) {
    const bf16x8 wf =
        *(const bf16x8*)(dW1at + (size_t)(ct * 16 + l16) * 32 + quad * 8);
    f32x4 a = {};
    a = MFMA16(wf, af2, a);
    const int col0 = ct * 16 + quad * 4;
    const bf16x4 pd = *(const bf16x4*)(preD + (size_t)prow * 1024 + col0);
    bf16x4 o;
#pragma unroll
    for (int r = 0; r < 4; ++r) o[r] = (bf16)silu(a[r] + (float)pd[r]);
    *(bf16x4*)(Hd + (size_t)row * 1024 + col0) = o;
  }
}

// ---- unified prep: coalesced tiled transposes + vbias + init ----------
// Block ranges (64x64 LDS-tiled transpose, out[n*K+k] = in[(k+ro)*ldin+n]):
//  [0,64)    pW1  -> pdW1vt          K=256  N=1024
//  [64,128)  dW1z -> pdW1vt+1024*256 K=256  N=1024
//  [128,192) vW1z -> pdW1vt+2048*256 K=256  N=1024
//  [192,448) pW2  -> pW2t            K=1024 N=1024
//  [448,704) dW2  -> dW2t            K=1024 N=1024
//  [704,960) vW2  -> vW2t            K=1024 N=1024
//  [960,1024) dW3 -> dW3t            K=1024 N=256
//  [1024,1040) dW1a -> dW1at         K=32   N=1024 ro=256
//  [1040,1056) pWm -> pHt            K=1024 N=32
//  [1056,1072) pWs -> pHt+32*1024    K=1024 N=32
//  1072       pdb1
//  [1073,1093) vbias (5*1024 elems)
//  [1093,1093+4096) init: wave-per-row Zf/Zb0/sz0/efe/sn/sc
__global__ __launch_bounds__(256) void prep_tr(
    const float* __restrict__ pW1, const float* __restrict__ dW1,
    const float* __restrict__ vW1, const float* __restrict__ pW2,
    const float* __restrict__ dW2, const float* __restrict__ dW3,
    const float* __restrict__ vW2, const float* __restrict__ pWm,
    const float* __restrict__ pWs, const float* __restrict__ pb1,
    const float* __restrict__ db1, const float* __restrict__ vb1,
    const float* __restrict__ latent, bf16* __restrict__ pdW1vt,
    bf16* __restrict__ pW2t, bf16* __restrict__ pHt,
    bf16* __restrict__ dW1at, bf16* __restrict__ dW2t,
    bf16* __restrict__ dW3t, bf16* __restrict__ vW2t,
    float* __restrict__ pdb1, float* __restrict__ vbias,
    float* __restrict__ Zf, bf16* __restrict__ Zb0, float* __restrict__ efe,
    float* __restrict__ sz0, float* __restrict__ snAll,
    float* __restrict__ scAll) {
  int bid = blockIdx.x;
  if (bid == 1072) {  // pdb1
    for (int i = threadIdx.x; i < 2048; i += 256)
      pdb1[i] = (i < 1024) ? pb1[i] : db1[i - 1024];
    return;
  }
  if (bid >= 1073 && bid < 1093) {  // vbias
    const int idx = (bid - 1073) * 256 + threadIdx.x;  // < 5120
    const int t = idx >> 10, j = idx & 1023;
    float s = vb1[j];
    const float lt = (float)t;
    for (int i = 0; i < 64; ++i) {
      const float f = expf(-9.210340371976184f * (float)i / 64.f);
      const float ang = lt * f;
      s += sinf(ang) * vW1[(size_t)(256 + i) * 1024 + j];
      s += cosf(ang) * vW1[(size_t)(256 + 64 + i) * 1024 + j];
    }
    vbias[idx] = s;
    return;
  }
  if (bid >= 1093) {  // init: 4 rows/block, wave per row
    const int wave = threadIdx.x >> 6, lane = threadIdx.x & 63;
    const int row = (bid - 1093) * 4 + wave;
    const f32x4 z = *(const f32x4*)(latent + (size_t)(row & 1023) * 256 + lane * 4);
    *(f32x4*)(Zf + (size_t)row * 256 + lane * 4) = z;
    if (row < 1024) {
      bf16x4 o = {(bf16)z[0], (bf16)z[1], (bf16)z[2], (bf16)z[3]};
      *(bf16x4*)(Zb0 + (size_t)row * 256 + lane * 4) = o;
    }
    float s = z[0] * z[0] + z[1] * z[1] + z[2] * z[2] + z[3] * z[3];
#pragma unroll
    for (int m = 1; m < 64; m <<= 1) s += __shfl_xor(s, m);
    if (lane == 0) {
      sz0[row] = s;
      efe[row] = 0.f;
    }
    if (lane < HORIZON) {
      snAll[lane * MR + row] = 0.f;
      scAll[lane * MR + row] = 0.f;
    }
    return;
  }
  // ---- tiled transpose segments ----
  const float* in;
  bf16* out;
  int K, N, ldin, ro = 0;
  if (bid < 64) { in = pW1; out = pdW1vt; K = 256; N = 1024; ldin = 1024; }
  else if (bid < 128) { bid -= 64; in = dW1; out = pdW1vt + 1024 * 256; K = 256; N = 1024; ldin = 1024; }
  else if (bid < 192) { bid -= 128; in = vW1; out = pdW1vt + 2048 * 256; K = 256; N = 1024; ldin = 1024; }
  else if (bid < 448) { bid -= 192; in = pW2; out = pW2t; K = 1024; N = 1024; ldin = 1024; }
  else if (bid < 704) { bid -= 448; in = dW2; out = dW2t; K = 1024; N = 1024; ldin = 1024; }
  else if (bid < 960) { bid -= 704; in = vW2; out = vW2t; K = 1024; N = 1024; ldin = 1024; }
  else if (bid < 1024) { bid -= 960; in = dW3; out = dW3t; K = 1024; N = 256; ldin = 256; }
  else if (bid < 1040) { bid -= 1024; in = dW1; out = dW1at; K = 32; N = 1024; ldin = 1024; ro = 256; }
  else if (bid < 1056) { bid -= 1040; in = pWm; out = pHt; K = 1024; N = 32; ldin = 32; }
  else { bid -= 1056; in = pWs; out = pHt + 32 * 1024; K = 1024; N = 32; ldin = 32; }

  const int ktiles = (K + 63) >> 6;
  const int k0 = (bid % ktiles) * 64, n0 = (bid / ktiles) * 64;
  __shared__ float tile[64][65];
  const int tx = threadIdx.x & 63, ty = threadIdx.x >> 6;
#pragma unroll
  for (int i = 0; i < 16; ++i) {
    const int k = k0 + ty + i * 4;
    if (k < K && n0 + tx < N)
      tile[ty + i * 4][tx] = in[(size_t)(ro + k) * ldin + n0 + tx];
  }
  __syncthreads();
#pragma unroll
  for (int i = 0; i < 16; ++i) {
    const int n = n0 + ty + i * 4;
    if (n < N && k0 + tx < K)
      out[(size_t)n * K + k0 + tx] = (bf16)tile[tx][ty + i * 4];
  }
}

__global__ void finalize(const float* __restrict__ efe,
                         const float* __restrict__ vb3,
                         float* __restrict__ out) {
  const int b = blockIdx.x * 256 + threadIdx.x;  // 1024
  float s = 0.f;
#pragma unroll
  for (int n = 0; n < 16; ++n) s += efe[n * 1024 + b];
  out[b] = s * (1.f / 16.f) + SUMDISC * vb3[0];
}

extern "C" void kernel_launch(void* const* d_in, const int* in_sizes, int n_in,
                              void* d_out, int out_size, void* d_ws,
                              size_t ws_size, hipStream_t stream) {
  const float* latent = (const float*)d_in[0];
  const float* noise = (const float*)d_in[1];
  const float* pW1 = (const float*)d_in[2];
  const float* pb1 = (const float*)d_in[3];
  const float* pW2 = (const float*)d_in[4];
  const float* pb2 = (const float*)d_in[5];
  const float* pWm = (const float*)d_in[6];
  const float* pbm = (const float*)d_in[7];
  const float* pWs = (const float*)d_in[8];
  const float* pbs = (const float*)d_in[9];
  const float* dW1 = (const float*)d_in[10];
  const float* db1 = (const float*)d_in[11];
  const float* dW2 = (const float*)d_in[12];
  const float* db2 = (const float*)d_in[13];
  const float* dW3 = (const float*)d_in[14];
  const float* db3 = (const float*)d_in[15];
  const float* vW1 = (const float*)d_in[16];
  const float* vb1 = (const float*)d_in[17];
  const float* vW2 = (const float*)d_in[18];
  const float* vb2 = (const float*)d_in[19];
  const float* vW3 = (const float*)d_in[20];
  const float* vb3 = (const float*)d_in[21];

  char* w = (char*)d_ws;
  size_t off = 0;
  auto take = [&](size_t bytes) -> void* {
    void* p = (void*)(w + off);
    off = (off + bytes + 255) & ~(size_t)255;
    return p;
  };
  bf16* pdW1vt = (bf16*)take(3072ull * 256 * 2);  // [pW1|dW1z|vW1]^T
  float* pdb1 = (float*)take(2048ull * 4);
  bf16* pW2t = (bf16*)take(1024ull * 1024 * 2);
  bf16* pHt = (bf16*)take(64ull * 1024 * 2);
  bf16* dW1at = (bf16*)take(1024ull * 32 * 2);
  bf16* dW2t = (bf16*)take(1024ull * 1024 * 2);
  bf16* dW3t = (bf16*)take(256ull * 1024 * 2);
  bf16* vW2t = (bf16*)take(1024ull * 1024 * 2);
  float* vbias = (float*)take(5ull * 1024 * 4);
  bf16* Zb0 = (bf16*)take(1024ull * 256 * 2);      // z0 bf16, shared rows
  bf16* Zb = (bf16*)take((size_t)MR * 256 * 2);    // z_t bf16 (single buf)
  float* Zf = (float*)take((size_t)MR * 256 * 4);  // fp32 master z
  float* efe = (float*)take((size_t)MR * 4);
  float* sz0 = (float*)take((size_t)MR * 4);
  float* snAll = (float*)take(5ull * MR * 4);
  float* scAll = (float*)take(5ull * MR * 4);
  bf16* Ha = (bf16*)take((size_t)MR * 1024 * 2);
  bf16* Hc = (bf16*)take((size_t)MR * 1024 * 2);
  bf16* Hp = (bf16*)take((size_t)MR * 1024 * 2);
  bf16* Hv = (bf16*)take((size_t)MR * 1024 * 2);
  bf16* vW1t = pdW1vt + (size_t)2048 * 256;  // value-L1 weights (tail step)

  const dim3 blk(256);
  const int BIG = 1 << 30;
  // prep_tr: 1072 transpose tiles + pdb1 + 20 vbias + 4096 init blocks
  prep_tr<<<dim3(1093 + MR / 4), blk, 0, stream>>>(
      pW1, dW1, vW1, pW2, dW2, dW3, vW2, pWm, pWs, pb1, db1, vb1, latent,
      pdW1vt, pW2t, pHt, dW1at, dW2t, dW3t, vW2t, pdb1, vbias, Zf, Zb0, efe,
      sz0, snAll, scAll);

  float disc = 1.f, dprev = 1.f;
  for (int s = 0; s < HORIZON; ++s) {
    const int rmask = (s == 0) ? 1023 : 0x7FFFFFFF;
    if (s == 0) {
      // [policy L1 | dyn L1z] only: M=1024 (shared latent), N=2048
      gemm128<<<dim3(8, 16), blk, 0, stream>>>(Zb0, 256, 256, pdW1vt, pdb1,
                                               1024, Ha, Hp, 1024);
      // policy L2 at M=1024
      gemm128<<<dim3(8, 8), blk, 0, stream>>>(Ha, 1024, 1024, pW2t, pb2, BIG,
                                              Hc, Hc, 1024);
    } else {
      // trunk + value-L1 for pragmatic(s-1) on z_s: N=3072
      gemm_pd1v<<<dim3(128, 24), blk, 0, stream>>>(
          Zb, pdW1vt, pdb1, vbias + (s - 1) * 1024, Ha, Hp, Hv);
      // policy L2
      gemm128<<<dim3(128, 8), blk, 0, stream>>>(Ha, 1024, 1024, pW2t, pb2, BIG,
                                                Hc, Hc, 1024);
      // value L2 + vW3 dot -> efe (pragmatic of step s-1)
      gemm_vdot<<<dim3(128, 8), blk, 0, stream>>>(Hv, vW2t, vb2, vW3, efe,
                                                  dprev);
    }
    // heads + dyn-L1 completion: Hc,Hp (masked rows) -> action/ent, Hd -> Ha
    heads3<<<dim3(MR / 64), blk, 0, stream>>>(Hc, pHt, pbm, pbs, noise, Hp,
                                              dW1at, Ha, efe, s, disc, rmask);
    // dynamics L2: Ha -> Hc
    gemm128<<<dim3(128, 8), blk, 0, stream>>>(Ha, 1024, 1024, dW2t, db2, BIG,
                                              Hc, Hc, 1024);
    // dynamics L3 fused with z_next / KL partials; writes Zb = z_{s+1}
    gemm_dyn3<<<dim3(MR / 64, 2), blk, 0, stream>>>(
        Hc, dW3t, db3, Zf, Zb, snAll + (size_t)s * MR, scAll + (size_t)s * MR);
    dprev = disc;
    disc *= 0.99f;
  }

  kl_batch<<<dim3(MR / 256), blk, 0, stream>>>(sz0, snAll, scAll, efe);

  // final pragmatic(4) on z_5: value L1 then L2+dot
  gemm128<<<dim3(128, 8), blk, 0, stream>>>(Zb, 256, 256, vW1t,
                                            vbias + 4 * 1024, BIG, Hv, Hv,
                                            1024);
  gemm_vdot<<<dim3(128, 8), blk, 0, stream>>>(Hv, vW2t, vb2, vW3, efe, dprev);
  finalize<<<dim3(4), blk, 0, stream>>>(efe, vb3, (float*)d_out);
}

// Round 9
// 1374.002 us; speedup vs baseline: 1.3004x; 1.0610x over previous
//
#include <hip/hip_runtime.h>
#include <cstdint>
#include <cstddef>
#include <cmath>

// DiffusionActiveInference on MI355X (gfx950).
// R9: heads3 -> heads4 split-K redesign. Old heads3: 256 blocks = 1
// block/CU, 16 barrier-pairs serialized against load latency (MfmaUtil 2%,
// VALUBusy 13%, Occ 10%, 57.5us). heads4: 16 rows/block, 4 waves own
// K-quarters, LDS cross-wave reduce, completion split 16 col-tiles/wave.
// Grid MR/16 = 1024 blocks = 4/CU. All other kernels byte-identical to R8.

typedef __bf16 bf16;
typedef __attribute__((ext_vector_type(8))) __bf16 bf16x8;
typedef __attribute__((ext_vector_type(4))) __bf16 bf16x4;
typedef __attribute__((ext_vector_type(4))) float f32x4;

static constexpr int BATCH = 1024, NTRAJ = 16, HORIZON = 5;
static constexpr int MR = NTRAJ * BATCH;  // 16384 GEMM rows
static constexpr float ENT_C = 1.4189385332046727f;  // 0.5*(1+log(2*pi))
static constexpr float SUMDISC = 4.90099501f;        // sum 0.99^t, t=0..4

// ---- async global->LDS, 16B per lane ----------------------------------
__device__ __forceinline__ void gld_lds16(const bf16* g, const bf16* l) {
  typedef __attribute__((address_space(1))) const uint32_t gq_t;
  typedef __attribute__((address_space(3))) uint32_t lq_t;
  gq_t* gp = (gq_t*)(uintptr_t)g;
  lq_t* lp = (lq_t*)(uint32_t)(uintptr_t)l;
  __builtin_amdgcn_global_load_lds(gp, lp, 16, 0, 0);
}

__device__ __forceinline__ float silu(float x) {
  return x / (1.f + __expf(-x));
}

#define MFMA16(a, b, c) __builtin_amdgcn_mfma_f32_16x16x32_bf16((a), (b), (c), 0, 0, 0)

// ---- generic GEMM: C = maybe_silu(A[M,K](lda) @ Bt[N,K]^T + bias) -----
// grid (M/128, N/128) ROW-major (x=row -> XCD affinity). BK=64 dual panels.
__global__ __launch_bounds__(256) void gemm128(
    const bf16* __restrict__ A, int lda, int K, const bf16* __restrict__ Bt,
    const float* __restrict__ bias, int act_cols,
    bf16* __restrict__ C1, bf16* __restrict__ C2, int ldc) {
  __shared__ alignas(16) bf16 As0[128 * 32], As1[128 * 32];
  __shared__ alignas(16) bf16 Bs0[128 * 32], Bs1[128 * 32];
  const int tid = threadIdx.x, wave = tid >> 6, lane = tid & 63;
  const int quad = lane >> 4, l16 = lane & 15;
  const int rowBlk = blockIdx.x * 128, colBlk = blockIdx.y * 128;
  const int wr = wave >> 1, wc = wave & 1;
  const int srow = lane >> 2, skel = (lane & 3) * 8;

  const bf16* gA0 = A + (size_t)(rowBlk + wave * 32 + srow) * lda + skel;
  const bf16* gA1 = gA0 + (size_t)16 * lda;
  const bf16* gB0 = Bt + (size_t)(colBlk + wave * 32 + srow) * K + skel;
  const bf16* gB1 = gB0 + (size_t)16 * K;
  bf16* const lA0 = As0 + wave * 32 * 32;
  bf16* const lA0b = As0 + (wave * 32 + 16) * 32;
  bf16* const lA1 = As1 + wave * 32 * 32;
  bf16* const lA1b = As1 + (wave * 32 + 16) * 32;
  bf16* const lB0 = Bs0 + wave * 32 * 32;
  bf16* const lB0b = Bs0 + (wave * 32 + 16) * 32;
  bf16* const lB1 = Bs1 + wave * 32 * 32;
  bf16* const lB1b = Bs1 + (wave * 32 + 16) * 32;

  f32x4 acc[4][4] = {};
  for (int k0 = 0; k0 < K; k0 += 64) {
    gld_lds16(gA0 + k0, lA0);
    gld_lds16(gA1 + k0, lA0b);
    gld_lds16(gA0 + k0 + 32, lA1);
    gld_lds16(gA1 + k0 + 32, lA1b);
    gld_lds16(gB0 + k0, lB0);
    gld_lds16(gB1 + k0, lB0b);
    gld_lds16(gB0 + k0 + 32, lB1);
    gld_lds16(gB1 + k0 + 32, lB1b);
    __syncthreads();
#pragma unroll
    for (int ks = 0; ks < 2; ++ks) {
      const bf16* aRd = (ks ? As1 : As0) + (wr * 64 + l16) * 32 + quad * 8;
      const bf16* bRd = (ks ? Bs1 : Bs0) + (wc * 64 + l16) * 32 + quad * 8;
      bf16x8 af[4], bfr[4];
#pragma unroll
      for (int i = 0; i < 4; ++i) {
        af[i] = *(const bf16x8*)(aRd + i * 16 * 32);
        bfr[i] = *(const bf16x8*)(bRd + i * 16 * 32);
      }
#pragma unroll
      for (int mi = 0; mi < 4; ++mi)
#pragma unroll
        for (int ni = 0; ni < 4; ++ni)
          acc[mi][ni] = MFMA16(bfr[ni], af[mi], acc[mi][ni]);
    }
    __syncthreads();
  }

  const bool doAct = (colBlk < act_cols);
  bf16* const Cp = doAct ? C1 : C2;
  const int cShift = doAct ? 0 : act_cols;
#pragma unroll
  for (int mi = 0; mi < 4; ++mi) {
    const int row = rowBlk + wr * 64 + mi * 16 + l16;
#pragma unroll
    for (int ni = 0; ni < 4; ++ni) {
      const int col0 = colBlk + wc * 64 + ni * 16 + quad * 4;
      const f32x4 bb = *(const f32x4*)(bias + col0);
      bf16x4 o;
#pragma unroll
      for (int r = 0; r < 4; ++r) {
        float x = acc[mi][ni][r] + bb[r];
        if (doAct) x = silu(x);
        o[r] = (bf16)x;
      }
      *(bf16x4*)(Cp + (size_t)row * ldc + (col0 - cShift)) = o;
    }
  }
}

// ---- per-step trunk: [policy-L1 | dyn-L1z | value-L1] in one GEMM -----
__global__ __launch_bounds__(256) void gemm_pd1v(
    const bf16* __restrict__ A, const bf16* __restrict__ Bt,
    const float* __restrict__ pdb1, const float* __restrict__ vbiasT,
    bf16* __restrict__ Ha, bf16* __restrict__ Hp, bf16* __restrict__ Hv) {
  __shared__ alignas(16) bf16 As0[128 * 32], As1[128 * 32];
  __shared__ alignas(16) bf16 Bs0[128 * 32], Bs1[128 * 32];
  const int tid = threadIdx.x, wave = tid >> 6, lane = tid & 63;
  const int quad = lane >> 4, l16 = lane & 15;
  const int rowBlk = blockIdx.x * 128, colBlk = blockIdx.y * 128;
  const int wr = wave >> 1, wc = wave & 1;
  const int srow = lane >> 2, skel = (lane & 3) * 8;

  const bf16* gA0 = A + (size_t)(rowBlk + wave * 32 + srow) * 256 + skel;
  const bf16* gA1 = gA0 + (size_t)16 * 256;
  const bf16* gB0 = Bt + (size_t)(colBlk + wave * 32 + srow) * 256 + skel;
  const bf16* gB1 = gB0 + (size_t)16 * 256;
  bf16* const lA0 = As0 + wave * 32 * 32;
  bf16* const lA0b = As0 + (wave * 32 + 16) * 32;
  bf16* const lA1 = As1 + wave * 32 * 32;
  bf16* const lA1b = As1 + (wave * 32 + 16) * 32;
  bf16* const lB0 = Bs0 + wave * 32 * 32;
  bf16* const lB0b = Bs0 + (wave * 32 + 16) * 32;
  bf16* const lB1 = Bs1 + wave * 32 * 32;
  bf16* const lB1b = Bs1 + (wave * 32 + 16) * 32;

  f32x4 acc[4][4] = {};
  for (int k0 = 0; k0 < 256; k0 += 64) {
    gld_lds16(gA0 + k0, lA0);
    gld_lds16(gA1 + k0, lA0b);
    gld_lds16(gA0 + k0 + 32, lA1);
    gld_lds16(gA1 + k0 + 32, lA1b);
    gld_lds16(gB0 + k0, lB0);
    gld_lds16(gB1 + k0, lB0b);
    gld_lds16(gB0 + k0 + 32, lB1);
    gld_lds16(gB1 + k0 + 32, lB1b);
    __syncthreads();
#pragma unroll
    for (int ks = 0; ks < 2; ++ks) {
      const bf16* aRd = (ks ? As1 : As0) + (wr * 64 + l16) * 32 + quad * 8;
      const bf16* bRd = (ks ? Bs1 : Bs0) + (wc * 64 + l16) * 32 + quad * 8;
      bf16x8 af[4], bfr[4];
#pragma unroll
      for (int i = 0; i < 4; ++i) {
        af[i] = *(const bf16x8*)(aRd + i * 16 * 32);
        bfr[i] = *(const bf16x8*)(bRd + i * 16 * 32);
      }
#pragma unroll
      for (int mi = 0; mi < 4; ++mi)
#pragma unroll
        for (int ni = 0; ni < 4; ++ni)
          acc[mi][ni] = MFMA16(bfr[ni], af[mi], acc[mi][ni]);
    }
    __syncthreads();
  }

  const int seg = colBlk >> 10;  // 0: policy, 1: dyn-z (linear), 2: value
  bf16* const Cp = (seg == 0) ? Ha : (seg == 1) ? Hp : Hv;
  const int cShift = seg << 10;
  const float* const bp = (seg == 2) ? (vbiasT - 2048) : pdb1;
#pragma unroll
  for (int mi = 0; mi < 4; ++mi) {
    const int row = rowBlk + wr * 64 + mi * 16 + l16;
#pragma unroll
    for (int ni = 0; ni < 4; ++ni) {
      const int col0 = colBlk + wc * 64 + ni * 16 + quad * 4;
      const f32x4 bb = *(const f32x4*)(bp + col0);
      bf16x4 o;
#pragma unroll
      for (int r = 0; r < 4; ++r) {
        float x = acc[mi][ni][r] + bb[r];
        if (seg != 1) x = silu(x);
        o[r] = (bf16)x;
      }
      *(bf16x4*)(Cp + (size_t)row * 1024 + (col0 - cShift)) = o;
    }
  }
}

// ---- value L2 + vW3 dot fused: efe += disc * silu(A@vW2+vb2).vW3 ------
__global__ __launch_bounds__(256) void gemm_vdot(
    const bf16* __restrict__ A, const bf16* __restrict__ Bt,
    const float* __restrict__ vb2, const float* __restrict__ vW3,
    float* __restrict__ efe, float disc) {
  __shared__ alignas(16) bf16 As0[128 * 32], As1[128 * 32];
  __shared__ alignas(16) bf16 Bs0[128 * 32], Bs1[128 * 32];
  const int tid = threadIdx.x, wave = tid >> 6, lane = tid & 63;
  const int quad = lane >> 4, l16 = lane & 15;
  const int rowBlk = blockIdx.x * 128, colBlk = blockIdx.y * 128;
  const int wr = wave >> 1, wc = wave & 1;
  const int srow = lane >> 2, skel = (lane & 3) * 8;

  const bf16* gA0 = A + (size_t)(rowBlk + wave * 32 + srow) * 1024 + skel;
  const bf16* gA1 = gA0 + (size_t)16 * 1024;
  const bf16* gB0 = Bt + (size_t)(colBlk + wave * 32 + srow) * 1024 + skel;
  const bf16* gB1 = gB0 + (size_t)16 * 1024;
  bf16* const lA0 = As0 + wave * 32 * 32;
  bf16* const lA0b = As0 + (wave * 32 + 16) * 32;
  bf16* const lA1 = As1 + wave * 32 * 32;
  bf16* const lA1b = As1 + (wave * 32 + 16) * 32;
  bf16* const lB0 = Bs0 + wave * 32 * 32;
  bf16* const lB0b = Bs0 + (wave * 32 + 16) * 32;
  bf16* const lB1 = Bs1 + wave * 32 * 32;
  bf16* const lB1b = Bs1 + (wave * 32 + 16) * 32;

  f32x4 acc[4][4] = {};
  for (int k0 = 0; k0 < 1024; k0 += 64) {
    gld_lds16(gA0 + k0, lA0);
    gld_lds16(gA1 + k0, lA0b);
    gld_lds16(gA0 + k0 + 32, lA1);
    gld_lds16(gA1 + k0 + 32, lA1b);
    gld_lds16(gB0 + k0, lB0);
    gld_lds16(gB1 + k0, lB0b);
    gld_lds16(gB0 + k0 + 32, lB1);
    gld_lds16(gB1 + k0 + 32, lB1b);
    __syncthreads();
#pragma unroll
    for (int ks = 0; ks < 2; ++ks) {
      const bf16* aRd = (ks ? As1 : As0) + (wr * 64 + l16) * 32 + quad * 8;
      const bf16* bRd = (ks ? Bs1 : Bs0) + (wc * 64 + l16) * 32 + quad * 8;
      bf16x8 af[4], bfr[4];
#pragma unroll
      for (int i = 0; i < 4; ++i) {
        af[i] = *(const bf16x8*)(aRd + i * 16 * 32);
        bfr[i] = *(const bf16x8*)(bRd + i * 16 * 32);
      }
#pragma unroll
      for (int mi = 0; mi < 4; ++mi)
#pragma unroll
        for (int ni = 0; ni < 4; ++ni)
          acc[mi][ni] = MFMA16(bfr[ni], af[mi], acc[mi][ni]);
    }
    __syncthreads();
  }

#pragma unroll
  for (int mi = 0; mi < 4; ++mi) {
    const int row = rowBlk + wr * 64 + mi * 16 + l16;
    float p = 0.f;
#pragma unroll
    for (int ni = 0; ni < 4; ++ni) {
      const int col0 = colBlk + wc * 64 + ni * 16 + quad * 4;
      const f32x4 bb = *(const f32x4*)(vb2 + col0);
      const f32x4 w3 = *(const f32x4*)(vW3 + col0);
#pragma unroll
      for (int r = 0; r < 4; ++r) p += silu(acc[mi][ni][r] + bb[r]) * w3[r];
    }
    p += __shfl_xor(p, 16);
    p += __shfl_xor(p, 32);
    if (quad == 0) atomicAdd(efe + row, disc * p);
  }
}

// ---- dynamics L3 + z_next + KL partials fused -------------------------
__global__ __launch_bounds__(256) void gemm_dyn3(
    const bf16* __restrict__ A, const bf16* __restrict__ Bt,
    const float* __restrict__ db3, float* __restrict__ Zf,
    bf16* __restrict__ Zb, float* __restrict__ s_n, float* __restrict__ s_c) {
  __shared__ alignas(16) bf16 As0[64 * 32], As1[64 * 32];
  __shared__ alignas(16) bf16 Bs0[128 * 32], Bs1[128 * 32];
  const int tid = threadIdx.x, wave = tid >> 6, lane = tid & 63;
  const int quad = lane >> 4, l16 = lane & 15;
  const int rowBlk = blockIdx.x * 64, colBlk = blockIdx.y * 128;
  const int srow = lane >> 2, skel = (lane & 3) * 8;

  const bf16* gA = A + (size_t)(rowBlk + wave * 16 + srow) * 1024 + skel;
  const bf16* gB0 = Bt + (size_t)(colBlk + wave * 32 + srow) * 1024 + skel;
  const bf16* gB1 = gB0 + (size_t)16 * 1024;
  bf16* const lA0 = As0 + wave * 16 * 32;
  bf16* const lA1 = As1 + wave * 16 * 32;
  bf16* const lB0 = Bs0 + wave * 32 * 32;
  bf16* const lB0b = Bs0 + (wave * 32 + 16) * 32;
  bf16* const lB1 = Bs1 + wave * 32 * 32;
  bf16* const lB1b = Bs1 + (wave * 32 + 16) * 32;

  f32x4 acc[8] = {};
  for (int k0 = 0; k0 < 1024; k0 += 64) {
    gld_lds16(gA + k0, lA0);
    gld_lds16(gA + k0 + 32, lA1);
    gld_lds16(gB0 + k0, lB0);
    gld_lds16(gB1 + k0, lB0b);
    gld_lds16(gB0 + k0 + 32, lB1);
    gld_lds16(gB1 + k0 + 32, lB1b);
    __syncthreads();
#pragma unroll
    for (int ks = 0; ks < 2; ++ks) {
      const bf16* aRd = (ks ? As1 : As0) + (wave * 16 + l16) * 32 + quad * 8;
      const bf16* bRd = (ks ? Bs1 : Bs0) + l16 * 32 + quad * 8;
      const bf16x8 af = *(const bf16x8*)aRd;
#pragma unroll
      for (int ni = 0; ni < 8; ++ni) {
        const bf16x8 bfr = *(const bf16x8*)(bRd + ni * 16 * 32);
        acc[ni] = MFMA16(bfr, af, acc[ni]);
      }
    }
    __syncthreads();
  }

  const int row = rowBlk + wave * 16 + l16;
  float pn = 0.f, pc = 0.f;
#pragma unroll
  for (int ni = 0; ni < 8; ++ni) {
    const int col0 = colBlk + ni * 16 + quad * 4;
    const f32x4 b4 = *(const f32x4*)(db3 + col0);
    float* zp = Zf + (size_t)row * 256 + col0;
    const f32x4 z = *(const f32x4*)zp;
    f32x4 zn;
    bf16x4 o;
#pragma unroll
    for (int r = 0; r < 4; ++r) {
      zn[r] = z[r] + acc[ni][r] + b4[r];
      pn += zn[r] * zn[r];
      pc += z[r] * zn[r];
      o[r] = (bf16)zn[r];
    }
    *(f32x4*)zp = zn;
    *(bf16x4*)(Zb + (size_t)row * 256 + col0) = o;
  }
  pn += __shfl_xor(pn, 16);
  pn += __shfl_xor(pn, 32);
  pc += __shfl_xor(pc, 16);
  pc += __shfl_xor(pc, 32);
  if (quad == 0) {
    atomicAdd(s_n + row, pn);
    atomicAdd(s_c + row, pc);
  }
}

// ---- batched KL epilogue: all 5 steps at once -------------------------
__global__ void kl_batch(const float* __restrict__ sz0,
                         const float* __restrict__ snAll,
                         const float* __restrict__ scAll,
                         float* __restrict__ efe) {
  const int m = blockIdx.x * 256 + threadIdx.x;
  float sz = sz0[m];
  float disc = 1.f, acc = 0.f;
  for (int t = 0; t < HORIZON; ++t) {
    const float sn = snAll[t * MR + m], sc = scAll[t * MR + m];
    const float nz = sqrtf(sz) + 1e-8f, nn = sqrtf(sn) + 1e-8f;
    const float kl =
        0.5f * (sz / (nz * nz) + sn / (nn * nn) - 2.f * sc / (nz * nn));
    acc += disc * log1pf(fmaxf(kl, 0.f));
    sz = sn;
    disc *= 0.99f;
  }
  efe[m] += acc;
}

// ---- heads4: split-K heads + dynamics-L1 completion -------------------
// grid (MR/16), block 256 (4 waves). Wave w owns K range [w*256, +256),
// BK=32 (8 iters). Cross-wave reduce via LDS (aliases Bs). All waves then
// redundantly compute action (wave0 writes LAct/efe); completion splits
// the 64 col-tiles 16/wave. rmask: H/preD row mask (1023 at t=0).
__global__ __launch_bounds__(256) void heads4(
    const bf16* __restrict__ H, const bf16* __restrict__ Wt,
    const float* __restrict__ pbm, const float* __restrict__ pbs,
    const float* __restrict__ noise, const bf16* __restrict__ preD,
    const bf16* __restrict__ dW1at, bf16* __restrict__ Hd,
    float* __restrict__ efe, int t, float disc, int rmask) {
  __shared__ alignas(16) bf16 As[4 * 16 * 32];   // per-wave A panel
  __shared__ alignas(16) bf16 Bs[4 * 64 * 32];   // per-wave B panel; f32 red after loop
  __shared__ alignas(16) bf16 LAct[16 * 32];
  const int tid = threadIdx.x, wave = tid >> 6, lane = tid & 63;
  const int quad = lane >> 4, l16 = lane & 15;
  const int rowBlk = blockIdx.x * 16;
  const int srow = lane >> 2, skel = (lane & 3) * 8;
  const int kw = wave * 256;

  const bf16* gA = H + (size_t)((rowBlk + srow) & rmask) * 1024 + kw + skel;
  bf16* const lA = As + wave * 16 * 32;
  bf16* const lB = Bs + wave * 64 * 32;

  f32x4 acc[4] = {};
  for (int k0 = 0; k0 < 256; k0 += 32) {
    gld_lds16(gA + k0, lA);
#pragma unroll
    for (int j = 0; j < 4; ++j)
      gld_lds16(Wt + (size_t)(j * 16 + srow) * 1024 + kw + k0 + skel,
                lB + j * 16 * 32);
    __syncthreads();
    const bf16x8 af = *(const bf16x8*)(lA + l16 * 32 + quad * 8);
#pragma unroll
    for (int ni = 0; ni < 4; ++ni) {
      const bf16x8 bfr = *(const bf16x8*)(lB + (ni * 16 + l16) * 32 + quad * 8);
      acc[ni] = MFMA16(bfr, af, acc[ni]);
    }
    __syncthreads();
  }

  // cross-wave reduction: partials through Bs-aliased f32 scratch (16KB)
  float* red = (float*)Bs;
#pragma unroll
  for (int ni = 0; ni < 4; ++ni)
    *(f32x4*)(red + wave * 1024 + ni * 256 + lane * 4) = acc[ni];
  __syncthreads();
#pragma unroll
  for (int ni = 0; ni < 4; ++ni) {
    f32x4 s = *(const f32x4*)(red + ni * 256 + lane * 4);
#pragma unroll
    for (int w2 = 1; w2 < 4; ++w2) {
      const f32x4 p = *(const f32x4*)(red + w2 * 1024 + ni * 256 + lane * 4);
#pragma unroll
      for (int r = 0; r < 4; ++r) s[r] += p[r];
    }
    acc[ni] = s;
  }

  // action + entropy (computed redundantly by all waves; wave0 writes)
  const int row = rowBlk + l16;
  const int n = row >> 10, b = row & 1023;
  float ent = 0.f;
#pragma unroll
  for (int ni = 0; ni < 2; ++ni) {
    const int col0 = ni * 16 + quad * 4;
    const f32x4 bm4 = *(const f32x4*)(pbm + col0);
    const f32x4 bs4 = *(const f32x4*)(pbs + col0);
    const f32x4 ep4 =
        *(const f32x4*)(noise + (((size_t)(n * 5 + t) * 1024 + b) * 32 + col0));
    bf16x4 o;
#pragma unroll
    for (int r = 0; r < 4; ++r) {
      const float mean = acc[ni][r] + bm4[r];
      float ls = acc[ni + 2][r] + bs4[r];
      ls = fminf(fmaxf(ls, -5.f), 2.f);
      o[r] = (bf16)(mean + __expf(ls) * ep4[r]);
      ent += ENT_C + ls;
    }
    if (wave == 0) *(bf16x4*)(LAct + l16 * 32 + col0) = o;
  }
  ent += __shfl_xor(ent, 16);
  ent += __shfl_xor(ent, 32);
  if (wave == 0 && quad == 0) efe[row] += disc * (-0.1f) * ent;
  __syncthreads();  // LAct ready

  // rank-32 completion: wave w handles col-tiles [w*16, w*16+16)
  const int prow = row & rmask;
  const bf16x8 af2 = *(const bf16x8*)(LAct + l16 * 32 + quad * 8);
#pragma unroll 4
  for (int ci = 0; ci < 16; ++ci) {
    const int ct = wave * 16 + ci;
    const bf16x8 wf =
        *(const bf16x8*)(dW1at + (size_t)(ct * 16 + l16) * 32 + quad * 8);
    f32x4 a = {};
    a = MFMA16(wf, af2, a);
    const int col0 = ct * 16 + quad * 4;
    const bf16x4 pd = *(const bf16x4*)(preD + (size_t)prow * 1024 + col0);
    bf16x4 o;
#pragma unroll
    for (int r = 0; r < 4; ++r) o[r] = (bf16)silu(a[r] + (float)pd[r]);
    *(bf16x4*)(Hd + (size_t)row * 1024 + col0) = o;
  }
}

// ---- unified prep: coalesced tiled transposes + vbias + init ----------
__global__ __launch_bounds__(256) void prep_tr(
    const float* __restrict__ pW1, const float* __restrict__ dW1,
    const float* __restrict__ vW1, const float* __restrict__ pW2,
    const float* __restrict__ dW2, const float* __restrict__ dW3,
    const float* __restrict__ vW2, const float* __restrict__ pWm,
    const float* __restrict__ pWs, const float* __restrict__ pb1,
    const float* __restrict__ db1, const float* __restrict__ vb1,
    const float* __restrict__ latent, bf16* __restrict__ pdW1vt,
    bf16* __restrict__ pW2t, bf16* __restrict__ pHt,
    bf16* __restrict__ dW1at, bf16* __restrict__ dW2t,
    bf16* __restrict__ dW3t, bf16* __restrict__ vW2t,
    float* __restrict__ pdb1, float* __restrict__ vbias,
    float* __restrict__ Zf, bf16* __restrict__ Zb0, float* __restrict__ efe,
    float* __restrict__ sz0, float* __restrict__ snAll,
    float* __restrict__ scAll) {
  int bid = blockIdx.x;
  if (bid == 1072) {  // pdb1
    for (int i = threadIdx.x; i < 2048; i += 256)
      pdb1[i] = (i < 1024) ? pb1[i] : db1[i - 1024];
    return;
  }
  if (bid >= 1073 && bid < 1093) {  // vbias
    const int idx = (bid - 1073) * 256 + threadIdx.x;  // < 5120
    const int t = idx >> 10, j = idx & 1023;
    float s = vb1[j];
    const float lt = (float)t;
    for (int i = 0; i < 64; ++i) {
      const float f = expf(-9.210340371976184f * (float)i / 64.f);
      const float ang = lt * f;
      s += sinf(ang) * vW1[(size_t)(256 + i) * 1024 + j];
      s += cosf(ang) * vW1[(size_t)(256 + 64 + i) * 1024 + j];
    }
    vbias[idx] = s;
    return;
  }
  if (bid >= 1093) {  // init: 4 rows/block, wave per row
    const int wave = threadIdx.x >> 6, lane = threadIdx.x & 63;
    const int row = (bid - 1093) * 4 + wave;
    const f32x4 z = *(const f32x4*)(latent + (size_t)(row & 1023) * 256 + lane * 4);
    *(f32x4*)(Zf + (size_t)row * 256 + lane * 4) = z;
    if (row < 1024) {
      bf16x4 o = {(bf16)z[0], (bf16)z[1], (bf16)z[2], (bf16)z[3]};
      *(bf16x4*)(Zb0 + (size_t)row * 256 + lane * 4) = o;
    }
    float s = z[0] * z[0] + z[1] * z[1] + z[2] * z[2] + z[3] * z[3];
#pragma unroll
    for (int m = 1; m < 64; m <<= 1) s += __shfl_xor(s, m);
    if (lane == 0) {
      sz0[row] = s;
      efe[row] = 0.f;
    }
    if (lane < HORIZON) {
      snAll[lane * MR + row] = 0.f;
      scAll[lane * MR + row] = 0.f;
    }
    return;
  }
  // ---- tiled transpose segments ----
  const float* in;
  bf16* out;
  int K, N, ldin, ro = 0;
  if (bid < 64) { in = pW1; out = pdW1vt; K = 256; N = 1024; ldin = 1024; }
  else if (bid < 128) { bid -= 64; in = dW1; out = pdW1vt + 1024 * 256; K = 256; N = 1024; ldin = 1024; }
  else if (bid < 192) { bid -= 128; in = vW1; out = pdW1vt + 2048 * 256; K = 256; N = 1024; ldin = 1024; }
  else if (bid < 448) { bid -= 192; in = pW2; out = pW2t; K = 1024; N = 1024; ldin = 1024; }
  else if (bid < 704) { bid -= 448; in = dW2; out = dW2t; K = 1024; N = 1024; ldin = 1024; }
  else if (bid < 960) { bid -= 704; in = vW2; out = vW2t; K = 1024; N = 1024; ldin = 1024; }
  else if (bid < 1024) { bid -= 960; in = dW3; out = dW3t; K = 1024; N = 256; ldin = 256; }
  else if (bid < 1040) { bid -= 1024; in = dW1; out = dW1at; K = 32; N = 1024; ldin = 1024; ro = 256; }
  else if (bid < 1056) { bid -= 1040; in = pWm; out = pHt; K = 1024; N = 32; ldin = 32; }
  else { bid -= 1056; in = pWs; out = pHt + 32 * 1024; K = 1024; N = 32; ldin = 32; }

  const int ktiles = (K + 63) >> 6;
  const int k0 = (bid % ktiles) * 64, n0 = (bid / ktiles) * 64;
  __shared__ float tile[64][65];
  const int tx = threadIdx.x & 63, ty = threadIdx.x >> 6;
#pragma unroll
  for (int i = 0; i < 16; ++i) {
    const int k = k0 + ty + i * 4;
    if (k < K && n0 + tx < N)
      tile[ty + i * 4][tx] = in[(size_t)(ro + k) * ldin + n0 + tx];
  }
  __syncthreads();
#pragma unroll
  for (int i = 0; i < 16; ++i) {
    const int n = n0 + ty + i * 4;
    if (n < N && k0 + tx < K)
      out[(size_t)n * K + k0 + tx] = (bf16)tile[tx][ty + i * 4];
  }
}

__global__ void finalize(const float* __restrict__ efe,
                         const float* __restrict__ vb3,
                         float* __restrict__ out) {
  const int b = blockIdx.x * 256 + threadIdx.x;  // 1024
  float s = 0.f;
#pragma unroll
  for (int n = 0; n < 16; ++n) s += efe[n * 1024 + b];
  out[b] = s * (1.f / 16.f) + SUMDISC * vb3[0];
}

extern "C" void kernel_launch(void* const* d_in, const int* in_sizes, int n_in,
                              void* d_out, int out_size, void* d_ws,
                              size_t ws_size, hipStream_t stream) {
  const float* latent = (const float*)d_in[0];
  const float* noise = (const float*)d_in[1];
  const float* pW1 = (const float*)d_in[2];
  const float* pb1 = (const float*)d_in[3];
  const float* pW2 = (const float*)d_in[4];
  const float* pb2 = (const float*)d_in[5];
  const float* pWm = (const float*)d_in[6];
  const float* pbm = (const float*)d_in[7];
  const float* pWs = (const float*)d_in[8];
  const float* pbs = (const float*)d_in[9];
  const float* dW1 = (const float*)d_in[10];
  const float* db1 = (const float*)d_in[11];
  const float* dW2 = (const float*)d_in[12];
  const float* db2 = (const float*)d_in[13];
  const float* dW3 = (const float*)d_in[14];
  const float* db3 = (const float*)d_in[15];
  const float* vW1 = (const float*)d_in[16];
  const float* vb1 = (const float*)d_in[17];
  const float* vW2 = (const float*)d_in[18];
  const float* vb2 = (const float*)d_in[19];
  const float* vW3 = (const float*)d_in[20];
  const float* vb3 = (const float*)d_in[21];

  char* w = (char*)d_ws;
  size_t off = 0;
  auto take = [&](size_t bytes) -> void* {
    void* p = (void*)(w + off);
    off = (off + bytes + 255) & ~(size_t)255;
    return p;
  };
  bf16* pdW1vt = (bf16*)take(3072ull * 256 * 2);  // [pW1|dW1z|vW1]^T
  float* pdb1 = (float*)take(2048ull * 4);
  bf16* pW2t = (bf16*)take(1024ull * 1024 * 2);
  bf16* pHt = (bf16*)take(64ull * 1024 * 2);
  bf16* dW1at = (bf16*)take(1024ull * 32 * 2);
  bf16* dW2t = (bf16*)take(1024ull * 1024 * 2);
  bf16* dW3t = (bf16*)take(256ull * 1024 * 2);
  bf16* vW2t = (bf16*)take(1024ull * 1024 * 2);
  float* vbias = (float*)take(5ull * 1024 * 4);
  bf16* Zb0 = (bf16*)take(1024ull * 256 * 2);      // z0 bf16, shared rows
  bf16* Zb = (bf16*)take((size_t)MR * 256 * 2);    // z_t bf16 (single buf)
  float* Zf = (float*)take((size_t)MR * 256 * 4);  // fp32 master z
  float* efe = (float*)take((size_t)MR * 4);
  float* sz0 = (float*)take((size_t)MR * 4);
  float* snAll = (float*)take(5ull * MR * 4);
  float* scAll = (float*)take(5ull * MR * 4);
  bf16* Ha = (bf16*)take((size_t)MR * 1024 * 2);
  bf16* Hc = (bf16*)take((size_t)MR * 1024 * 2);
  bf16* Hp = (bf16*)take((size_t)MR * 1024 * 2);
  bf16* Hv = (bf16*)take((size_t)MR * 1024 * 2);
  bf16* vW1t = pdW1vt + (size_t)2048 * 256;  // value-L1 weights (tail step)

  const dim3 blk(256);
  const int BIG = 1 << 30;
  // prep_tr: 1072 transpose tiles + pdb1 + 20 vbias + 4096 init blocks
  prep_tr<<<dim3(1093 + MR / 4), blk, 0, stream>>>(
      pW1, dW1, vW1, pW2, dW2, dW3, vW2, pWm, pWs, pb1, db1, vb1, latent,
      pdW1vt, pW2t, pHt, dW1at, dW2t, dW3t, vW2t, pdb1, vbias, Zf, Zb0, efe,
      sz0, snAll, scAll);

  float disc = 1.f, dprev = 1.f;
  for (int s = 0; s < HORIZON; ++s) {
    const int rmask = (s == 0) ? 1023 : 0x7FFFFFFF;
    if (s == 0) {
      // [policy L1 | dyn L1z] only: M=1024 (shared latent), N=2048
      gemm128<<<dim3(8, 16), blk, 0, stream>>>(Zb0, 256, 256, pdW1vt, pdb1,
                                               1024, Ha, Hp, 1024);
      // policy L2 at M=1024
      gemm128<<<dim3(8, 8), blk, 0, stream>>>(Ha, 1024, 1024, pW2t, pb2, BIG,
                                              Hc, Hc, 1024);
    } else {
      // trunk + value-L1 for pragmatic(s-1) on z_s: N=3072
      gemm_pd1v<<<dim3(128, 24), blk, 0, stream>>>(
          Zb, pdW1vt, pdb1, vbias + (s - 1) * 1024, Ha, Hp, Hv);
      // policy L2
      gemm128<<<dim3(128, 8), blk, 0, stream>>>(Ha, 1024, 1024, pW2t, pb2, BIG,
                                                Hc, Hc, 1024);
      // value L2 + vW3 dot -> efe (pragmatic of step s-1)
      gemm_vdot<<<dim3(128, 8), blk, 0, stream>>>(Hv, vW2t, vb2, vW3, efe,
                                                  dprev);
    }
    // heads + dyn-L1 completion: Hc,Hp (masked rows) -> action/ent, Hd -> Ha
    heads4<<<dim3(MR / 16), blk, 0, stream>>>(Hc, pHt, pbm, pbs, noise, Hp,
                                              dW1at, Ha, efe, s, disc, rmask);
    // dynamics L2: Ha -> Hc
    gemm128<<<dim3(128, 8), blk, 0, stream>>>(Ha, 1024, 1024, dW2t, db2, BIG,
                                              Hc, Hc, 1024);
    // dynamics L3 fused with z_next / KL partials; writes Zb = z_{s+1}
    gemm_dyn3<<<dim3(MR / 64, 2), blk, 0, stream>>>(
        Hc, dW3t, db3, Zf, Zb, snAll + (size_t)s * MR, scAll + (size_t)s * MR);
    dprev = disc;
    disc *= 0.99f;
  }

  kl_batch<<<dim3(MR / 256), blk, 0, stream>>>(sz0, snAll, scAll, efe);

  // final pragmatic(4) on z_5: value L1 then L2+dot
  gemm128<<<dim3(128, 8), blk, 0, stream>>>(Zb, 256, 256, vW1t,
                                            vbias + 4 * 1024, BIG, Hv, Hv,
                                            1024);
  gemm_vdot<<<dim3(128, 8), blk, 0, stream>>>(Hv, vW2t, vb2, vW3, efe, dprev);
  finalize<<<dim3(4), blk, 0, stream>>>(efe, vb3, (float*)d_out);
}